// Round 1
// baseline (2015.602 us; speedup 1.0000x reference)
//
#include <hip/hip_runtime.h>
#include <float.h>

#define N_PATCH 100000
#define C 256
#define S_TOT 1344
#define NCHUNK 24
#define CHUNK 4167           // ceil(100000/24); last chunk = 4159
#define RG 32
#define NGRP 42              // 1344 / 32
#define KP 9

// ---------------- half squared norms of patches ----------------
__global__ void k_hp2(const float* __restrict__ patch, float* __restrict__ hp2) {
  int w = (blockIdx.x * blockDim.x + threadIdx.x) >> 6;   // one wave per patch row
  int lane = threadIdx.x & 63;
  if (w >= N_PATCH) return;
  float4 p = reinterpret_cast<const float4*>(patch + (size_t)w * C)[lane];
  float s = p.x*p.x + p.y*p.y + p.z*p.z + p.w*p.w;
  #pragma unroll
  for (int off = 32; off; off >>= 1) s += __shfl_down(s, off, 64);
  if (lane == 0) hp2[w] = 0.5f * s;
}

// ---------------- transpose all label embeddings to [c][row] ----------------
__global__ void k_lblT(const float* __restrict__ m, const float* __restrict__ g,
                       const float* __restrict__ s, float* __restrict__ lblT) {
  int i = blockIdx.x * blockDim.x + threadIdx.x;          // grid exactly covers 1344*256
  int r = i >> 8, c = i & 255;
  float v = (r < 64) ? m[(size_t)r * C + c]
          : (r < 320) ? g[(size_t)(r - 64) * C + c]
                      : s[(size_t)(r - 320) * C + c];
  lblT[(size_t)c * S_TOT + r] = v;
}

// ---------------- big scoring + per-chunk top-9 ----------------
// block: 256 threads, handles 32 label rows x one patch chunk.
// compute role: wave w -> rows r8..r8+7 ; lane pl -> patches pl+64*i (i=0..3)
// scan role:    thread -> row rs=tid>>3, lane-in-row li=tid&7
__global__ __launch_bounds__(256, 2) void k_score(
    const float* __restrict__ patch, const float* __restrict__ lblT,
    const float* __restrict__ hp2, float* __restrict__ candS, int* __restrict__ candI) {
  __shared__ float smem[64 * 257];                         // 65792 B; reused for scores + merge
  const int grp = blockIdx.x;                              // 0..41
  const int chunk = blockIdx.y;                            // 0..23
  const int row_base = grp * RG;
  const int p_begin = chunk * CHUNK;
  const int p_end = min(p_begin + CHUNK, N_PATCH);
  const int tid = threadIdx.x;
  const int pl = tid & 63;
  const int r8 = __builtin_amdgcn_readfirstlane((tid >> 6) << 3);  // uniform -> s_loads for labels
  const int rs = tid >> 3, li = tid & 7;

  float bs[KP]; int bi[KP];                                // per-thread top-9, sorted ascending
  #pragma unroll
  for (int j = 0; j < KP; ++j) { bs[j] = FLT_MAX; bi[j] = 0; }

  for (int tile = p_begin; tile < p_end; tile += 256) {
    const int tn = min(256, p_end - tile);
    float acc[8][4];
    #pragma unroll
    for (int r = 0; r < 8; ++r) {
      #pragma unroll
      for (int i = 0; i < 4; ++i) acc[r][i] = 0.f;
    }

    for (int cc = 0; cc < C; cc += 64) {
      __syncthreads();                                     // protect previous smem use
      {                                                    // stage 256 patches x 64 channels (transposed)
        const int cl = tid & 15;
        for (int pr = tid >> 4; pr < tn; pr += 16) {
          float4 v = reinterpret_cast<const float4*>(patch + (size_t)(tile + pr) * C + cc)[cl];
          smem[(4*cl+0)*257 + pr] = v.x;
          smem[(4*cl+1)*257 + pr] = v.y;
          smem[(4*cl+2)*257 + pr] = v.z;
          smem[(4*cl+3)*257 + pr] = v.w;
        }
      }
      __syncthreads();
      const float* lbase = lblT + (size_t)cc * S_TOT + row_base + r8;
      #pragma unroll 4
      for (int c = 0; c < 64; ++c) {
        float pv0 = smem[c*257 + pl];
        float pv1 = smem[c*257 + pl + 64];
        float pv2 = smem[c*257 + pl + 128];
        float pv3 = smem[c*257 + pl + 192];
        const float* lc = lbase + (size_t)c * S_TOT;
        #pragma unroll
        for (int r = 0; r < 8; ++r) {
          float lv = lc[r];                                // wave-uniform -> SGPR
          acc[r][0] = fmaf(lv, pv0, acc[r][0]);
          acc[r][1] = fmaf(lv, pv1, acc[r][1]);
          acc[r][2] = fmaf(lv, pv2, acc[r][2]);
          acc[r][3] = fmaf(lv, pv3, acc[r][3]);
        }
      }
    }
    __syncthreads();
    {                                                      // scores -> smem: s = 0.5*||p||^2 - l.p
      const int wv8 = (tid >> 6) << 3;
      #pragma unroll
      for (int i = 0; i < 4; ++i) {
        int p = pl + 64*i;
        float h = (p < tn) ? hp2[tile + p] : 0.f;
        #pragma unroll
        for (int r = 0; r < 8; ++r)
          smem[(wv8 + r)*257 + p] = (p < tn) ? (h - acc[r][i]) : FLT_MAX;
      }
    }
    __syncthreads();
    for (int j = li; j < 256; j += 8) {                    // scan: 8 lanes per row
      float s = smem[rs*257 + j];
      if (s < bs[KP-1]) {
        bs[KP-1] = s; bi[KP-1] = tile + j;
        #pragma unroll
        for (int q = KP-1; q >= 1; --q) {                  // compile-time-indexed bubble insert
          if (bs[q] < bs[q-1]) {
            float ts = bs[q]; bs[q] = bs[q-1]; bs[q-1] = ts;
            int ti = bi[q]; bi[q] = bi[q-1]; bi[q-1] = ti;
          }
        }
      }
    }
  }
  __syncthreads();
  // merge 8 lanes per row -> per-row chunk top-9
  float* cs = smem;                                        // [32][72]
  int* ci = (int*)(smem + RG * 72);                        // [32][72]
  #pragma unroll
  for (int j = 0; j < KP; ++j) {
    cs[rs*72 + li*KP + j] = bs[j];
    ci[rs*72 + li*KP + j] = bi[j];
  }
  __syncthreads();
  if (tid < RG) {
    float fs[KP]; int fi[KP];
    #pragma unroll
    for (int j = 0; j < KP; ++j) { fs[j] = FLT_MAX; fi[j] = 0; }
    for (int q = 0; q < 72; ++q) {
      float s = cs[tid*72 + q];
      if (s < fs[KP-1]) {
        fs[KP-1] = s; fi[KP-1] = ci[tid*72 + q];
        #pragma unroll
        for (int qq = KP-1; qq >= 1; --qq) {
          if (fs[qq] < fs[qq-1]) {
            float ts = fs[qq]; fs[qq] = fs[qq-1]; fs[qq-1] = ts;
            int ti = fi[qq]; fi[qq] = fi[qq-1]; fi[qq-1] = ti;
          }
        }
      }
    }
    size_t o = ((size_t)(row_base + tid) * NCHUNK + chunk) * KP;
    #pragma unroll
    for (int j = 0; j < KP; ++j) { candS[o+j] = fs[j]; candI[o+j] = fi[j]; }
  }
}

// ---------------- merge per-chunk candidates -> final top-9 indices ----------------
__global__ void k_merge(const float* __restrict__ candS, const int* __restrict__ candI,
                        int* __restrict__ idxOut) {
  int row = blockIdx.x * blockDim.x + threadIdx.x;
  if (row >= S_TOT) return;
  float fs[KP]; int fi[KP];
  #pragma unroll
  for (int j = 0; j < KP; ++j) { fs[j] = FLT_MAX; fi[j] = 0; }
  const float* s = candS + (size_t)row * NCHUNK * KP;
  const int* ix = candI + (size_t)row * NCHUNK * KP;
  for (int q = 0; q < NCHUNK*KP; ++q) {
    float v = s[q];
    if (v < fs[KP-1]) {
      fs[KP-1] = v; fi[KP-1] = ix[q];
      #pragma unroll
      for (int qq = KP-1; qq >= 1; --qq) {
        if (fs[qq] < fs[qq-1]) {
          float ts = fs[qq]; fs[qq] = fs[qq-1]; fs[qq-1] = ts;
          int ti = fi[qq]; fi[qq] = fi[qq-1]; fi[qq-1] = ti;
        }
      }
    }
  }
  #pragma unroll
  for (int j = 0; j < KP; ++j) idxOut[(size_t)row*KP + j] = fi[j];
}

// ---------------- ctx from patch: max_j patch[idx_j][c] - label[c] ----------------
__global__ void k_ctx_patch(const float* __restrict__ patch, const float* __restrict__ lbl,
                            const int* __restrict__ idx, int row0, float* __restrict__ ctx) {
  int row = blockIdx.x, c = threadIdx.x;
  const int* id = idx + (size_t)(row0 + row) * KP;
  float m = -FLT_MAX;
  #pragma unroll
  for (int j = 0; j < KP; ++j) m = fmaxf(m, patch[(size_t)id[j] * C + c]);
  ctx[(size_t)row*C + c] = m - lbl[(size_t)row*C + c];
}

// ---------------- ctx from another (updated) label set, k<=4, nref<=256 ----------------
__global__ void k_ctx_lbl(const float* __restrict__ q, const float* __restrict__ ref,
                          int nref, int k, float* __restrict__ ctx) {
  __shared__ float qs[C];
  __shared__ float ds[256];
  __shared__ int sel[4];
  int row = blockIdx.x, t = threadIdx.x;
  qs[t] = q[(size_t)row*C + t];
  __syncthreads();
  if (t < nref) {
    float s = 0.f;
    for (int c = 0; c < C; ++c) { float d = qs[c] - ref[(size_t)t*C + c]; s = fmaf(d, d, s); }
    ds[t] = s;
  }
  __syncthreads();
  if (t == 0) {
    for (int j = 0; j < k; ++j) {
      float best = FLT_MAX; int b = 0;
      for (int q2 = 0; q2 < nref; ++q2) if (ds[q2] < best) { best = ds[q2]; b = q2; }
      sel[j] = b; ds[b] = FLT_MAX;
    }
  }
  __syncthreads();
  float m = -FLT_MAX;
  for (int j = 0; j < k; ++j) m = fmaxf(m, ref[(size_t)sel[j]*C + t]);
  ctx[(size_t)row*C + t] = m - qs[t];
}

// ---------------- fused concat @ W + bias + residual + LayerNorm ----------------
__global__ __launch_bounds__(256) void k_out(
    const float* __restrict__ emb, const float* __restrict__ c0,
    const float* __restrict__ c1, const float* __restrict__ c2,
    const float* __restrict__ W, const float* __restrict__ bias,
    const float* __restrict__ gamma, const float* __restrict__ beta,
    float* __restrict__ out, int nin) {
  __shared__ float x[1024];
  __shared__ float red[4];
  int row = blockIdx.x, t = threadIdx.x;
  float e = emb[(size_t)row*C + t];
  x[t] = e;
  x[C + t] = c0[(size_t)row*C + t];
  if (c1) x[2*C + t] = c1[(size_t)row*C + t];
  if (c2) x[3*C + t] = c2[(size_t)row*C + t];
  __syncthreads();
  float s = bias[t];
  #pragma unroll 4
  for (int i = 0; i < nin; ++i) s = fmaf(x[i], W[(size_t)i*C + t], s);
  float y = e + s;
  float sum = y;
  #pragma unroll
  for (int off = 32; off; off >>= 1) sum += __shfl_down(sum, off, 64);
  if ((t & 63) == 0) red[t >> 6] = sum;
  __syncthreads();
  float mu = (red[0] + red[1] + red[2] + red[3]) * (1.f/C);
  __syncthreads();
  float d = y - mu;
  float sq = d*d;
  #pragma unroll
  for (int off = 32; off; off >>= 1) sq += __shfl_down(sq, off, 64);
  if ((t & 63) == 0) red[t >> 6] = sq;
  __syncthreads();
  float var = (red[0] + red[1] + red[2] + red[3]) * (1.f/C);
  float r = rsqrtf(var + 1e-5f);
  out[(size_t)row*C + t] = d * r * gamma[t] + beta[t];
}

extern "C" void kernel_launch(void* const* d_in, const int* in_sizes, int n_in,
                              void* d_out, int out_size, void* d_ws, size_t ws_size,
                              hipStream_t stream) {
  const float* patch   = (const float*)d_in[0];
  const float* mood_e  = (const float*)d_in[1];
  const float* genre_e = (const float*)d_in[2];
  const float* sub_e   = (const float*)d_in[3];
  const float* Wm  = (const float*)d_in[4];
  const float* bm  = (const float*)d_in[5];
  const float* Wg  = (const float*)d_in[6];
  const float* bg  = (const float*)d_in[7];
  const float* Ws  = (const float*)d_in[8];
  const float* bs_ = (const float*)d_in[9];
  const float* gm  = (const float*)d_in[10];
  const float* bnm = (const float*)d_in[11];
  const float* gg  = (const float*)d_in[12];
  const float* bng = (const float*)d_in[13];
  const float* gs  = (const float*)d_in[14];
  const float* bns = (const float*)d_in[15];

  char* ws = (char*)d_ws;
  size_t off = 0;
  auto alloc = [&](size_t bytes) { void* p = ws + off; off = (off + bytes + 255) & ~(size_t)255; return p; };
  float* hp2   = (float*)alloc((size_t)N_PATCH * 4);
  float* lblT  = (float*)alloc((size_t)C * S_TOT * 4);
  float* candS = (float*)alloc((size_t)S_TOT * NCHUNK * KP * 4);
  int*   candI = (int*)  alloc((size_t)S_TOT * NCHUNK * KP * 4);
  int*   idx   = (int*)  alloc((size_t)S_TOT * KP * 4);
  float* ctx_m  = (float*)alloc((size_t)64   * C * 4);
  float* ctx_gp = (float*)alloc((size_t)256  * C * 4);
  float* ctx_gm = (float*)alloc((size_t)256  * C * 4);
  float* ctx_sp = (float*)alloc((size_t)1024 * C * 4);
  float* ctx_sm = (float*)alloc((size_t)1024 * C * 4);
  float* ctx_sg = (float*)alloc((size_t)1024 * C * 4);

  float* out_m = (float*)d_out;
  float* out_g = out_m + 64 * C;
  float* out_s = out_g + 256 * C;

  k_hp2<<<N_PATCH/4, 256, 0, stream>>>(patch, hp2);
  k_lblT<<<(S_TOT*C)/256, 256, 0, stream>>>(mood_e, genre_e, sub_e, lblT);
  k_score<<<dim3(NGRP, NCHUNK), 256, 0, stream>>>(patch, lblT, hp2, candS, candI);
  k_merge<<<(S_TOT+255)/256, 256, 0, stream>>>(candS, candI, idx);
  k_ctx_patch<<<64,   256, 0, stream>>>(patch, mood_e,  idx, 0,   ctx_m);
  k_ctx_patch<<<256,  256, 0, stream>>>(patch, genre_e, idx, 64,  ctx_gp);
  k_ctx_patch<<<1024, 256, 0, stream>>>(patch, sub_e,   idx, 320, ctx_sp);
  k_out<<<64, 256, 0, stream>>>(mood_e, ctx_m, nullptr, nullptr, Wm, bm, gm, bnm, out_m, 512);
  k_ctx_lbl<<<256, 256, 0, stream>>>(genre_e, out_m, 64, 4, ctx_gm);
  k_out<<<256, 256, 0, stream>>>(genre_e, ctx_gp, ctx_gm, nullptr, Wg, bg, gg, bng, out_g, 768);
  k_ctx_lbl<<<1024, 256, 0, stream>>>(sub_e, out_m, 64, 3, ctx_sm);
  k_ctx_lbl<<<1024, 256, 0, stream>>>(sub_e, out_g, 256, 4, ctx_sg);
  k_out<<<1024, 256, 0, stream>>>(sub_e, ctx_sp, ctx_sm, ctx_sg, Ws, bs_, gs, bns, out_s, 1024);
}

// Round 2
// 778.173 us; speedup vs baseline: 2.5902x; 2.5902x over previous
//
#include <hip/hip_runtime.h>
#include <float.h>

#define N_PATCH 100000
#define C 256
#define S_TOT 1344
#define LBLK 32
#define NGRP 42              // 1344/32
#define NCHUNK 24
#define CHUNKP 4167          // ceil(100000/24)
#define PTILE 64
#define KC 10                // approx candidates kept per (row, lane-subset) and per (row, chunk)
#define KP 9

typedef __attribute__((ext_vector_type(8))) short bf16x8;
typedef __attribute__((ext_vector_type(4))) float f32x4;
typedef __attribute__((ext_vector_type(4))) unsigned int u32x4;

static __device__ __forceinline__ unsigned short f2bf(float f) {
  unsigned int u = __float_as_uint(f);
  return (unsigned short)((u + 0x7FFFu + ((u >> 16) & 1u)) >> 16);
}

// ---------------- patches: fp32 -> bf16 rows + half squared norms ----------------
__global__ __launch_bounds__(256) void k_prep(const float* __restrict__ patch,
                                              unsigned short* __restrict__ patchB,
                                              float* __restrict__ hp2) {
  int row = (blockIdx.x * blockDim.x + threadIdx.x) >> 6;
  int l = threadIdx.x & 63;
  if (row >= N_PATCH) return;
  float4 p = reinterpret_cast<const float4*>(patch + (size_t)row * C)[l];
  ushort4 h;
  h.x = f2bf(p.x); h.y = f2bf(p.y); h.z = f2bf(p.z); h.w = f2bf(p.w);
  *reinterpret_cast<ushort4*>(patchB + (size_t)row * C + l * 4) = h;
  float s = p.x*p.x + p.y*p.y + p.z*p.z + p.w*p.w;
  #pragma unroll
  for (int off = 32; off; off >>= 1) s += __shfl_down(s, off, 64);
  if (l == 0) hp2[row] = 0.5f * s;
}

// ---------------- labels: concat fp32 + bf16 ----------------
__global__ __launch_bounds__(64) void k_preplbl(const float* __restrict__ m,
                                                const float* __restrict__ g,
                                                const float* __restrict__ s,
                                                unsigned short* __restrict__ lblB,
                                                float* __restrict__ lblF) {
  int row = blockIdx.x, l = threadIdx.x;
  const float* src = (row < 64) ? m + (size_t)row * C
                   : (row < 320) ? g + (size_t)(row - 64) * C
                                 : s + (size_t)(row - 320) * C;
  float4 v = reinterpret_cast<const float4*>(src)[l];
  reinterpret_cast<float4*>(lblF + (size_t)row * C)[l] = v;
  ushort4 h;
  h.x = f2bf(v.x); h.y = f2bf(v.y); h.z = f2bf(v.z); h.w = f2bf(v.w);
  *reinterpret_cast<ushort4*>(lblB + (size_t)row * C + l * 4) = h;
}

#define INS(BS, BI, SV, PV)                                         \
  if ((SV) < BS[KC-1]) {                                            \
    BS[KC-1] = (SV); BI[KC-1] = (PV);                               \
    _Pragma("unroll")                                               \
    for (int _q = KC-1; _q >= 1; --_q) {                            \
      if (BS[_q] < BS[_q-1]) {                                      \
        float _t = BS[_q]; BS[_q] = BS[_q-1]; BS[_q-1] = _t;        \
        int _ti = BI[_q]; BI[_q] = BI[_q-1]; BI[_q-1] = _ti;        \
      }                                                             \
    }                                                               \
  }

// ---------------- MFMA scoring: 32 labels x patch chunk, per-lane top-10 ----------------
__global__ __launch_bounds__(256, 2) void k_score_mfma(
    const char* __restrict__ patchB, const char* __restrict__ lblB,
    const float* __restrict__ hp2,
    float* __restrict__ candS, int* __restrict__ candI) {
  __shared__ char smem[49152];
  char* patchS = smem;               // 32 KB: 64 rows x 512 B, swizzled
  char* lblS   = smem + 32768;       // 16 KB: 32 rows x 512 B, swizzled

  const int grp = blockIdx.x, chunk = blockIdx.y;
  const int row0 = grp * LBLK;
  const int p_begin = chunk * CHUNKP;
  const int p_end = min(p_begin + CHUNKP, N_PATCH);
  const int tid = threadIdx.x;
  const int l = tid & 63, w = tid >> 6;

  // stage labels (16 KB), swizzled
  #pragma unroll
  for (int it = 0; it < 4; ++it) {
    int u = it * 256 + tid;
    int r = u >> 5; int b = (u & 31) << 4;
    u32x4 v = *reinterpret_cast<const u32x4*>(lblB + (((size_t)(row0 + r)) << 9) + b);
    *reinterpret_cast<u32x4*>(lblS + (r << 9) + (b ^ ((r & 7) << 4))) = v;
  }
  __syncthreads();

  // B fragments: 2 n-tiles x 8 k-steps, in registers for the whole block
  const int kq = (l >> 4) << 4;
  bf16x8 bf[2][8];
  #pragma unroll
  for (int nt = 0; nt < 2; ++nt) {
    int r = nt * 16 + (l & 15);
    int xm = (r & 7) << 4;
    #pragma unroll
    for (int ks = 0; ks < 8; ++ks)
      bf[nt][ks] = *reinterpret_cast<const bf16x8*>(lblS + (r << 9) + ((ks * 64 + kq) ^ xm));
  }

  float bs0[KC], bs1[KC]; int bi0[KC], bi1[KC];
  #pragma unroll
  for (int j = 0; j < KC; ++j) { bs0[j] = FLT_MAX; bs1[j] = FLT_MAX; bi0[j] = 0; bi1[j] = 0; }

  const int ntiles = (p_end - p_begin + PTILE - 1) / PTILE;
  const int prA = (w << 4) + (l & 15);          // A-row (patch) within tile for this lane
  const int xmA = (prA & 7) << 4;
  const int psub = (w << 4) + ((l >> 4) << 2);  // D-row base: patch_local = psub + r
  const char* abase = patchS + (prA << 9);

  for (int t = 0; t < ntiles; ++t) {
    const int tile0 = p_begin + t * PTILE;
    __syncthreads();
    // stage 64 x 512 B patch tile (reg-staged, swizzled LDS writes)
    u32x4 stg[8];
    #pragma unroll
    for (int it = 0; it < 8; ++it) {
      int u = it * 256 + tid;
      int pr = u >> 5; int b = (u & 31) << 4;
      int pg = tile0 + pr; if (pg >= N_PATCH) pg = N_PATCH - 1;
      stg[it] = *reinterpret_cast<const u32x4*>(patchB + (((size_t)pg) << 9) + b);
    }
    #pragma unroll
    for (int it = 0; it < 8; ++it) {
      int u = it * 256 + tid;
      int pr = u >> 5; int b = (u & 31) << 4;
      *reinterpret_cast<u32x4*>(patchS + (pr << 9) + (b ^ ((pr & 7) << 4))) = stg[it];
    }
    __syncthreads();

    f32x4 acc0 = {0.f, 0.f, 0.f, 0.f}, acc1 = {0.f, 0.f, 0.f, 0.f};
    #pragma unroll
    for (int ks = 0; ks < 8; ++ks) {
      bf16x8 a = *reinterpret_cast<const bf16x8*>(abase + ((ks * 64 + kq) ^ xmA));
      acc0 = __builtin_amdgcn_mfma_f32_16x16x32_bf16(a, bf[0][ks], acc0, 0, 0, 0);
      acc1 = __builtin_amdgcn_mfma_f32_16x16x32_bf16(a, bf[1][ks], acc1, 0, 0, 0);
    }

    const int pg0 = tile0 + psub;
    float h[4];
    #pragma unroll
    for (int r = 0; r < 4; ++r) h[r] = hp2[min(pg0 + r, N_PATCH - 1)];
    #pragma unroll
    for (int r = 0; r < 4; ++r) {
      int pg = pg0 + r;
      if (pg < p_end) {
        float s0 = h[r] - acc0[r];
        float s1 = h[r] - acc1[r];
        INS(bs0, bi0, s0, pg);
        INS(bs1, bi1, s1, pg);
      }
    }
  }
  __syncthreads();

  // merge 16 lane-subsets per label -> per (row, chunk) top-10
  float* ms = reinterpret_cast<float*>(smem);            // [32][16][KC]
  int* mi = reinterpret_cast<int*>(smem + 32 * 16 * KC * 4);
  const int sub = (w << 2) + (l >> 4);
  {
    int L = l & 15;
    #pragma unroll
    for (int j = 0; j < KC; ++j) {
      ms[(L * 16 + sub) * KC + j] = bs0[j];
      mi[(L * 16 + sub) * KC + j] = bi0[j];
      ms[((L + 16) * 16 + sub) * KC + j] = bs1[j];
      mi[((L + 16) * 16 + sub) * KC + j] = bi1[j];
    }
  }
  __syncthreads();
  if (tid < LBLK) {
    float fs[KC]; int fi[KC];
    #pragma unroll
    for (int j = 0; j < KC; ++j) { fs[j] = FLT_MAX; fi[j] = 0; }
    for (int q = 0; q < 16 * KC; ++q) {
      float v = ms[tid * 16 * KC + q];
      int p = mi[tid * 16 * KC + q];
      INS(fs, fi, v, p);
    }
    size_t o = ((size_t)(row0 + tid) * NCHUNK + chunk) * KC;
    #pragma unroll
    for (int j = 0; j < KC; ++j) { candS[o + j] = fs[j]; candI[o + j] = fi[j]; }
  }
}

// ---------------- exact fp32 rescore of 240 candidates -> top-9 indices ----------------
__global__ __launch_bounds__(256) void k_rescore(
    const float* __restrict__ patchF, const float* __restrict__ lblF,
    const float* __restrict__ hp2, const int* __restrict__ candI,
    int* __restrict__ idxOut) {
  __shared__ float lrow[C];
  __shared__ float ss[NCHUNK * KC];
  __shared__ int si[NCHUNK * KC];
  int row = blockIdx.x, t = threadIdx.x;
  lrow[t] = lblF[(size_t)row * C + t];
  __syncthreads();
  if (t < NCHUNK * KC) {
    int p = candI[(size_t)row * NCHUNK * KC + t];
    const float4* pr = reinterpret_cast<const float4*>(patchF + (size_t)p * C);
    const float4* lr = reinterpret_cast<const float4*>(lrow);
    float d = 0.f;
    #pragma unroll 8
    for (int i = 0; i < 64; ++i) {
      float4 a = pr[i], b = lr[i];
      d = fmaf(a.x, b.x, d); d = fmaf(a.y, b.y, d);
      d = fmaf(a.z, b.z, d); d = fmaf(a.w, b.w, d);
    }
    ss[t] = hp2[p] - d;
    si[t] = p;
  }
  __syncthreads();
  if (t == 0) {
    float fs[KP]; int fi[KP];
    #pragma unroll
    for (int j = 0; j < KP; ++j) { fs[j] = FLT_MAX; fi[j] = 0; }
    for (int q = 0; q < NCHUNK * KC; ++q) {
      float v = ss[q];
      if (v < fs[KP-1]) {
        fs[KP-1] = v; fi[KP-1] = si[q];
        #pragma unroll
        for (int qq = KP-1; qq >= 1; --qq) {
          if (fs[qq] < fs[qq-1]) {
            float ts = fs[qq]; fs[qq] = fs[qq-1]; fs[qq-1] = ts;
            int ti = fi[qq]; fi[qq] = fi[qq-1]; fi[qq-1] = ti;
          }
        }
      }
    }
    #pragma unroll
    for (int j = 0; j < KP; ++j) idxOut[(size_t)row * KP + j] = fi[j];
  }
}

// ---------------- ctx from patch: max_j patch[idx_j][c] - label[c] ----------------
__global__ void k_ctx_patch(const float* __restrict__ patch, const float* __restrict__ lbl,
                            const int* __restrict__ idx, int row0, float* __restrict__ ctx) {
  int row = blockIdx.x, c = threadIdx.x;
  const int* id = idx + (size_t)(row0 + row) * KP;
  float m = -FLT_MAX;
  #pragma unroll
  for (int j = 0; j < KP; ++j) m = fmaxf(m, patch[(size_t)id[j] * C + c]);
  ctx[(size_t)row * C + c] = m - lbl[(size_t)row * C + c];
}

// ---------------- ctx from an updated label set, k<=4, nref<=256 ----------------
__global__ void k_ctx_lbl(const float* __restrict__ q, const float* __restrict__ ref,
                          int nref, int k, float* __restrict__ ctx) {
  __shared__ float qs[C];
  __shared__ float ds[256];
  __shared__ int sel[4];
  int row = blockIdx.x, t = threadIdx.x;
  qs[t] = q[(size_t)row * C + t];
  __syncthreads();
  if (t < nref) {
    float s = 0.f;
    for (int c = 0; c < C; ++c) { float d = qs[c] - ref[(size_t)t * C + c]; s = fmaf(d, d, s); }
    ds[t] = s;
  }
  __syncthreads();
  if (t == 0) {
    for (int j = 0; j < k; ++j) {
      float best = FLT_MAX; int b = 0;
      for (int q2 = 0; q2 < nref; ++q2) if (ds[q2] < best) { best = ds[q2]; b = q2; }
      sel[j] = b; ds[b] = FLT_MAX;
    }
  }
  __syncthreads();
  float m = -FLT_MAX;
  for (int j = 0; j < k; ++j) m = fmaxf(m, ref[(size_t)sel[j] * C + t]);
  ctx[(size_t)row * C + t] = m - qs[t];
}

// ---------------- fused concat @ W + bias + residual + LayerNorm, 4 rows/block ----------------
__global__ __launch_bounds__(256) void k_out4(
    const float* __restrict__ emb, const float* __restrict__ c0,
    const float* __restrict__ c1, const float* __restrict__ c2,
    const float* __restrict__ W, const float* __restrict__ bias,
    const float* __restrict__ gamma, const float* __restrict__ beta,
    float* __restrict__ out, int nin) {
  __shared__ float x[4][1024];
  __shared__ float red[4][4];    // [wave][row]
  int row0 = blockIdx.x * 4, t = threadIdx.x;
  float e[4];
  #pragma unroll
  for (int rr = 0; rr < 4; ++rr) {
    size_t o = (size_t)(row0 + rr) * C + t;
    e[rr] = emb[o];
    x[rr][t] = e[rr];
    x[rr][C + t] = c0[o];
    if (c1) x[rr][2 * C + t] = c1[o];
    if (c2) x[rr][3 * C + t] = c2[o];
  }
  __syncthreads();
  float s[4] = {0.f, 0.f, 0.f, 0.f};
  for (int i = 0; i < nin; ++i) {
    float wv = W[(size_t)i * C + t];
    #pragma unroll
    for (int rr = 0; rr < 4; ++rr) s[rr] = fmaf(x[rr][i], wv, s[rr]);
  }
  float bv = bias[t];
  float y[4], d[4];
  int wv_ = t >> 6, ln = t & 63;
  #pragma unroll
  for (int rr = 0; rr < 4; ++rr) {
    y[rr] = e[rr] + s[rr] + bv;
    float sum = y[rr];
    #pragma unroll
    for (int off = 32; off; off >>= 1) sum += __shfl_down(sum, off, 64);
    if (ln == 0) red[wv_][rr] = sum;
  }
  __syncthreads();
  float mu[4];
  #pragma unroll
  for (int rr = 0; rr < 4; ++rr)
    mu[rr] = (red[0][rr] + red[1][rr] + red[2][rr] + red[3][rr]) * (1.f / C);
  __syncthreads();
  #pragma unroll
  for (int rr = 0; rr < 4; ++rr) {
    d[rr] = y[rr] - mu[rr];
    float sq = d[rr] * d[rr];
    #pragma unroll
    for (int off = 32; off; off >>= 1) sq += __shfl_down(sq, off, 64);
    if (ln == 0) red[wv_][rr] = sq;
  }
  __syncthreads();
  #pragma unroll
  for (int rr = 0; rr < 4; ++rr) {
    float var = (red[0][rr] + red[1][rr] + red[2][rr] + red[3][rr]) * (1.f / C);
    out[(size_t)(row0 + rr) * C + t] = d[rr] * rsqrtf(var + 1e-5f) * gamma[t] + beta[t];
  }
}

extern "C" void kernel_launch(void* const* d_in, const int* in_sizes, int n_in,
                              void* d_out, int out_size, void* d_ws, size_t ws_size,
                              hipStream_t stream) {
  const float* patch   = (const float*)d_in[0];
  const float* mood_e  = (const float*)d_in[1];
  const float* genre_e = (const float*)d_in[2];
  const float* sub_e   = (const float*)d_in[3];
  const float* Wm  = (const float*)d_in[4];
  const float* bm  = (const float*)d_in[5];
  const float* Wg  = (const float*)d_in[6];
  const float* bg  = (const float*)d_in[7];
  const float* Ws  = (const float*)d_in[8];
  const float* bs_ = (const float*)d_in[9];
  const float* gm  = (const float*)d_in[10];
  const float* bnm = (const float*)d_in[11];
  const float* gg  = (const float*)d_in[12];
  const float* bng = (const float*)d_in[13];
  const float* gs  = (const float*)d_in[14];
  const float* bns = (const float*)d_in[15];

  char* ws = (char*)d_ws;
  size_t off = 0;
  auto alloc = [&](size_t bytes) { void* p = ws + off; off = (off + bytes + 255) & ~(size_t)255; return p; };
  unsigned short* patchB = (unsigned short*)alloc((size_t)N_PATCH * C * 2);   // 51.2 MB
  unsigned short* lblB   = (unsigned short*)alloc((size_t)S_TOT * C * 2);
  float* lblF  = (float*)alloc((size_t)S_TOT * C * 4);
  float* hp2   = (float*)alloc((size_t)N_PATCH * 4);
  float* candS = (float*)alloc((size_t)S_TOT * NCHUNK * KC * 4);
  int*   candI = (int*)  alloc((size_t)S_TOT * NCHUNK * KC * 4);
  int*   idx   = (int*)  alloc((size_t)S_TOT * KP * 4);
  float* ctx_m  = (float*)alloc((size_t)64   * C * 4);
  float* ctx_gp = (float*)alloc((size_t)256  * C * 4);
  float* ctx_gm = (float*)alloc((size_t)256  * C * 4);
  float* ctx_sp = (float*)alloc((size_t)1024 * C * 4);
  float* ctx_sm = (float*)alloc((size_t)1024 * C * 4);
  float* ctx_sg = (float*)alloc((size_t)1024 * C * 4);

  float* out_m = (float*)d_out;
  float* out_g = out_m + 64 * C;
  float* out_s = out_g + 256 * C;

  k_prep<<<N_PATCH / 4, 256, 0, stream>>>(patch, patchB, hp2);
  k_preplbl<<<S_TOT, 64, 0, stream>>>(mood_e, genre_e, sub_e, lblB, lblF);
  k_score_mfma<<<dim3(NGRP, NCHUNK), 256, 0, stream>>>((const char*)patchB, (const char*)lblB,
                                                       hp2, candS, candI);
  k_rescore<<<S_TOT, 256, 0, stream>>>(patch, lblF, hp2, candI, idx);
  k_ctx_patch<<<64,   256, 0, stream>>>(patch, mood_e,  idx, 0,   ctx_m);
  k_ctx_patch<<<256,  256, 0, stream>>>(patch, genre_e, idx, 64,  ctx_gp);
  k_ctx_patch<<<1024, 256, 0, stream>>>(patch, sub_e,   idx, 320, ctx_sp);
  k_out4<<<16, 256, 0, stream>>>(mood_e, ctx_m, nullptr, nullptr, Wm, bm, gm, bnm, out_m, 512);
  k_ctx_lbl<<<256, 256, 0, stream>>>(genre_e, out_m, 64, 4, ctx_gm);
  k_out4<<<64, 256, 0, stream>>>(genre_e, ctx_gp, ctx_gm, nullptr, Wg, bg, gg, bng, out_g, 768);
  k_ctx_lbl<<<1024, 256, 0, stream>>>(sub_e, out_m, 64, 3, ctx_sm);
  k_ctx_lbl<<<1024, 256, 0, stream>>>(sub_e, out_g, 256, 4, ctx_sg);
  k_out4<<<256, 256, 0, stream>>>(sub_e, ctx_sp, ctx_sm, ctx_sg, Ws, bs_, gs, bns, out_s, 1024);
}

// Round 3
// 489.474 us; speedup vs baseline: 4.1179x; 1.5898x over previous
//
#include <hip/hip_runtime.h>
#include <float.h>

#define N_PATCH 100000
#define C 256
#define S_TOT 1344
#define LBLK 32
#define NGRP 42              // 1344/32
#define NCHUNK 18
#define CHUNKP 5556          // ceil(100000/18); last chunk = 5548
#define PTILE 64
#define KCL 4                // per-lane kept candidates
#define KCC 10               // per-(row,chunk) kept candidates
#define KP 9

typedef __attribute__((ext_vector_type(8))) short bf16x8;
typedef __attribute__((ext_vector_type(4))) float f32x4;
typedef __attribute__((ext_vector_type(4))) unsigned int u32x4;

static __device__ __forceinline__ unsigned short f2bf(float f) {
  unsigned int u = __float_as_uint(f);
  return (unsigned short)((u + 0x7FFFu + ((u >> 16) & 1u)) >> 16);
}

// ---------------- patches: fp32 -> bf16 rows + half squared norms ----------------
__global__ __launch_bounds__(256) void k_prep(const float* __restrict__ patch,
                                              unsigned short* __restrict__ patchB,
                                              float* __restrict__ hp2) {
  int row = (blockIdx.x * blockDim.x + threadIdx.x) >> 6;
  int l = threadIdx.x & 63;
  if (row >= N_PATCH) return;
  float4 p = reinterpret_cast<const float4*>(patch + (size_t)row * C)[l];
  ushort4 h;
  h.x = f2bf(p.x); h.y = f2bf(p.y); h.z = f2bf(p.z); h.w = f2bf(p.w);
  *reinterpret_cast<ushort4*>(patchB + (size_t)row * C + l * 4) = h;
  float s = p.x*p.x + p.y*p.y + p.z*p.z + p.w*p.w;
  #pragma unroll
  for (int off = 32; off; off >>= 1) s += __shfl_down(s, off, 64);
  if (l == 0) hp2[row] = 0.5f * s;
}

// ---------------- labels: concat fp32 + bf16 ----------------
__global__ __launch_bounds__(64) void k_preplbl(const float* __restrict__ m,
                                                const float* __restrict__ g,
                                                const float* __restrict__ s,
                                                unsigned short* __restrict__ lblB,
                                                float* __restrict__ lblF) {
  int row = blockIdx.x, l = threadIdx.x;
  const float* src = (row < 64) ? m + (size_t)row * C
                   : (row < 320) ? g + (size_t)(row - 64) * C
                                 : s + (size_t)(row - 320) * C;
  float4 v = reinterpret_cast<const float4*>(src)[l];
  reinterpret_cast<float4*>(lblF + (size_t)row * C)[l] = v;
  ushort4 h;
  h.x = f2bf(v.x); h.y = f2bf(v.y); h.z = f2bf(v.z); h.w = f2bf(v.w);
  *reinterpret_cast<ushort4*>(lblB + (size_t)row * C + l * 4) = h;
}

// branchless insert of (SV, IV) into sorted-ascending 4-lists
#define BINS(B, I, SV, IV)                                  \
  {                                                         \
    bool c0 = (SV) < B##0, c1 = (SV) < B##1,                \
         c2 = (SV) < B##2, c3 = (SV) < B##3;                \
    I##3 = c2 ? I##2 : (c3 ? (IV) : I##3);                  \
    I##2 = c1 ? I##1 : (c2 ? (IV) : I##2);                  \
    I##1 = c0 ? I##0 : (c1 ? (IV) : I##1);                  \
    I##0 = c0 ? (IV) : I##0;                                \
    B##3 = fminf(B##3, fmaxf(B##2, (SV)));                  \
    B##2 = fminf(B##2, fmaxf(B##1, (SV)));                  \
    B##1 = fminf(B##1, fmaxf(B##0, (SV)));                  \
    B##0 = fminf(B##0, (SV));                               \
  }

// ---------------- MFMA scoring: 32 labels x patch chunk, branchless per-lane top-4 ----------------
__global__ __launch_bounds__(256, 3) void k_score_mfma(
    const char* __restrict__ patchB, const char* __restrict__ lblB,
    const float* __restrict__ hp2,
    float* __restrict__ candS, int* __restrict__ candI) {
  __shared__ char patchS[32768];                 // 64 rows x 512 B, swizzled
  __shared__ char lblS[16384];                   // 32 rows x 512 B, swizzled
  __shared__ __align__(16) float hpS[64];

  const int grp = blockIdx.x, chunk = blockIdx.y;
  const int row0 = grp * LBLK;
  const int p_begin = chunk * CHUNKP;
  const int p_end = min(p_begin + CHUNKP, N_PATCH);
  const int tid = threadIdx.x;
  const int l = tid & 63, w = tid >> 6;

  // stage labels (16 KB), swizzled
  #pragma unroll
  for (int it = 0; it < 4; ++it) {
    int u = it * 256 + tid;
    int r = u >> 5; int b = (u & 31) << 4;
    u32x4 v = *reinterpret_cast<const u32x4*>(lblB + (((size_t)(row0 + r)) << 9) + b);
    *reinterpret_cast<u32x4*>(lblS + (r << 9) + (b ^ ((r & 7) << 4))) = v;
  }
  __syncthreads();

  // B fragments: 2 n-tiles x 8 k-steps, in registers for the whole block
  const int kq = (l >> 4) << 4;
  bf16x8 bf[2][8];
  #pragma unroll
  for (int nt = 0; nt < 2; ++nt) {
    int r = nt * 16 + (l & 15);
    int xm = (r & 7) << 4;
    #pragma unroll
    for (int ks = 0; ks < 8; ++ks)
      bf[nt][ks] = *reinterpret_cast<const bf16x8*>(lblS + (r << 9) + ((ks * 64 + kq) ^ xm));
  }

  // per-lane sorted top-4 for two labels (acc0-label, acc1-label)
  float a0, a1, a2, a3, b0, b1, b2, b3;
  int ia0, ia1, ia2, ia3, ib0, ib1, ib2, ib3;
  a0=a1=a2=a3=b0=b1=b2=b3=FLT_MAX;
  ia0=ia1=ia2=ia3=ib0=ib1=ib2=ib3=0;

  const int ntiles = (p_end - p_begin + PTILE - 1) / PTILE;
  const int prA = (w << 4) + (l & 15);
  const int xmA = (prA & 7) << 4;
  const int psub = (w << 4) + ((l >> 4) << 2);
  const char* abase = patchS + (prA << 9);
  const size_t glim = (size_t)N_PATCH * 512 - 16;

  u32x4 stg[8]; float4 hpre;
  auto prefetch = [&](int tile0) {
    size_t base = ((size_t)tile0 << 9) + ((size_t)tid << 4);
    #pragma unroll
    for (int it = 0; it < 8; ++it) {
      size_t a = base + (size_t)it * 4096;
      if (a > glim) a = glim;
      stg[it] = *reinterpret_cast<const u32x4*>(patchB + a);
    }
    if (tid < 16) {
      int hrow = tile0 + (tid << 2);
      if (hrow > N_PATCH - 4) hrow = N_PATCH - 4;
      hpre = *reinterpret_cast<const float4*>(hp2 + hrow);
    }
  };

  prefetch(p_begin);

  for (int t = 0; t < ntiles; ++t) {
    const int tile0 = p_begin + t * PTILE;
    __syncthreads();                             // previous tile's LDS reads done
    #pragma unroll
    for (int it = 0; it < 8; ++it) {
      int pr = it * 8 + (tid >> 5);
      int b = (tid & 31) << 4;
      *reinterpret_cast<u32x4*>(patchS + (pr << 9) + (b ^ ((pr & 7) << 4))) = stg[it];
    }
    if (tid < 16) *reinterpret_cast<float4*>(hpS + (tid << 2)) = hpre;
    if (t + 1 < ntiles) prefetch(tile0 + PTILE); // overlap next loads with compute
    __syncthreads();

    f32x4 acc0 = {0.f, 0.f, 0.f, 0.f}, acc1 = {0.f, 0.f, 0.f, 0.f};
    #pragma unroll
    for (int ks = 0; ks < 8; ++ks) {
      bf16x8 a = *reinterpret_cast<const bf16x8*>(abase + ((ks * 64 + kq) ^ xmA));
      acc0 = __builtin_amdgcn_mfma_f32_16x16x32_bf16(a, bf[0][ks], acc0, 0, 0, 0);
      acc1 = __builtin_amdgcn_mfma_f32_16x16x32_bf16(a, bf[1][ks], acc1, 0, 0, 0);
    }

    const int pg0 = tile0 + psub;
    float h0 = hpS[psub], h1 = hpS[psub + 1], h2 = hpS[psub + 2], h3 = hpS[psub + 3];
    if (tile0 + PTILE <= p_end) {                // fast path: all rows valid (wave-uniform)
      BINS(a, ia, h0 - acc0[0], pg0);
      BINS(a, ia, h1 - acc0[1], pg0 + 1);
      BINS(a, ia, h2 - acc0[2], pg0 + 2);
      BINS(a, ia, h3 - acc0[3], pg0 + 3);
      BINS(b, ib, h0 - acc1[0], pg0);
      BINS(b, ib, h1 - acc1[1], pg0 + 1);
      BINS(b, ib, h2 - acc1[2], pg0 + 2);
      BINS(b, ib, h3 - acc1[3], pg0 + 3);
    } else {
      float s0 = (pg0     < p_end) ? h0 - acc0[0] : FLT_MAX;
      float s1 = (pg0 + 1 < p_end) ? h1 - acc0[1] : FLT_MAX;
      float s2 = (pg0 + 2 < p_end) ? h2 - acc0[2] : FLT_MAX;
      float s3 = (pg0 + 3 < p_end) ? h3 - acc0[3] : FLT_MAX;
      float u0 = (pg0     < p_end) ? h0 - acc1[0] : FLT_MAX;
      float u1 = (pg0 + 1 < p_end) ? h1 - acc1[1] : FLT_MAX;
      float u2 = (pg0 + 2 < p_end) ? h2 - acc1[2] : FLT_MAX;
      float u3 = (pg0 + 3 < p_end) ? h3 - acc1[3] : FLT_MAX;
      BINS(a, ia, s0, pg0); BINS(a, ia, s1, pg0 + 1);
      BINS(a, ia, s2, pg0 + 2); BINS(a, ia, s3, pg0 + 3);
      BINS(b, ib, u0, pg0); BINS(b, ib, u1, pg0 + 1);
      BINS(b, ib, u2, pg0 + 2); BINS(b, ib, u3, pg0 + 3);
    }
  }
  __syncthreads();

  // merge 16 lane-subsets per label -> per (row, chunk) top-10
  float* ms = reinterpret_cast<float*>(patchS);            // [32][16][KCL] = 8 KB
  int* mi = reinterpret_cast<int*>(patchS + 8192);
  const int sub = (w << 2) + (l >> 4);
  const int L = l & 15;
  {
    int base0 = (L * 16 + sub) * KCL;
    int base1 = ((L + 16) * 16 + sub) * KCL;
    ms[base0 + 0] = a0; ms[base0 + 1] = a1; ms[base0 + 2] = a2; ms[base0 + 3] = a3;
    mi[base0 + 0] = ia0; mi[base0 + 1] = ia1; mi[base0 + 2] = ia2; mi[base0 + 3] = ia3;
    ms[base1 + 0] = b0; ms[base1 + 1] = b1; ms[base1 + 2] = b2; ms[base1 + 3] = b3;
    mi[base1 + 0] = ib0; mi[base1 + 1] = ib1; mi[base1 + 2] = ib2; mi[base1 + 3] = ib3;
  }
  __syncthreads();
  if (tid < LBLK) {
    float fs[KCC]; int fi[KCC];
    #pragma unroll
    for (int j = 0; j < KCC; ++j) { fs[j] = FLT_MAX; fi[j] = 0; }
    for (int q = 0; q < 16 * KCL; ++q) {
      float v = ms[tid * 16 * KCL + q];
      if (v < fs[KCC-1]) {
        fs[KCC-1] = v; fi[KCC-1] = mi[tid * 16 * KCL + q];
        #pragma unroll
        for (int qq = KCC-1; qq >= 1; --qq) {
          if (fs[qq] < fs[qq-1]) {
            float ts = fs[qq]; fs[qq] = fs[qq-1]; fs[qq-1] = ts;
            int ti = fi[qq]; fi[qq] = fi[qq-1]; fi[qq-1] = ti;
          }
        }
      }
    }
    size_t o = ((size_t)(row0 + tid) * NCHUNK + chunk) * KCC;
    #pragma unroll
    for (int j = 0; j < KCC; ++j) { candS[o + j] = fs[j]; candI[o + j] = fi[j]; }
  }
}

// ---------------- exact fp32 rescore of 180 candidates -> top-9 indices ----------------
__global__ __launch_bounds__(256) void k_rescore(
    const float* __restrict__ patchF, const float* __restrict__ lblF,
    const float* __restrict__ hp2, const int* __restrict__ candI,
    int* __restrict__ idxOut) {
  __shared__ float lrow[C];
  __shared__ float ss[NCHUNK * KCC];
  __shared__ int si[NCHUNK * KCC];
  int row = blockIdx.x, t = threadIdx.x;
  lrow[t] = lblF[(size_t)row * C + t];
  __syncthreads();
  if (t < NCHUNK * KCC) {
    int p = candI[(size_t)row * NCHUNK * KCC + t];
    const float4* pr = reinterpret_cast<const float4*>(patchF + (size_t)p * C);
    const float4* lr = reinterpret_cast<const float4*>(lrow);
    float d = 0.f;
    #pragma unroll 8
    for (int i = 0; i < 64; ++i) {
      float4 a = pr[i], b = lr[i];
      d = fmaf(a.x, b.x, d); d = fmaf(a.y, b.y, d);
      d = fmaf(a.z, b.z, d); d = fmaf(a.w, b.w, d);
    }
    ss[t] = hp2[p] - d;
    si[t] = p;
  }
  __syncthreads();
  if (t == 0) {
    float fs[KP]; int fi[KP];
    #pragma unroll
    for (int j = 0; j < KP; ++j) { fs[j] = FLT_MAX; fi[j] = 0; }
    for (int q = 0; q < NCHUNK * KCC; ++q) {
      float v = ss[q];
      if (v < fs[KP-1]) {
        fs[KP-1] = v; fi[KP-1] = si[q];
        #pragma unroll
        for (int qq = KP-1; qq >= 1; --qq) {
          if (fs[qq] < fs[qq-1]) {
            float ts = fs[qq]; fs[qq] = fs[qq-1]; fs[qq-1] = ts;
            int ti = fi[qq]; fi[qq] = fi[qq-1]; fi[qq-1] = ti;
          }
        }
      }
    }
    #pragma unroll
    for (int j = 0; j < KP; ++j) idxOut[(size_t)row * KP + j] = fi[j];
  }
}

// ---------------- ctx from patch: max_j patch[idx_j][c] - label[c] ----------------
__global__ void k_ctx_patch(const float* __restrict__ patch, const float* __restrict__ lbl,
                            const int* __restrict__ idx, int row0, float* __restrict__ ctx) {
  int row = blockIdx.x, c = threadIdx.x;
  const int* id = idx + (size_t)(row0 + row) * KP;
  float m = -FLT_MAX;
  #pragma unroll
  for (int j = 0; j < KP; ++j) m = fmaxf(m, patch[(size_t)id[j] * C + c]);
  ctx[(size_t)row * C + c] = m - lbl[(size_t)row * C + c];
}

// ---------------- ctx from an updated label set, wave-parallel argmin ----------------
__global__ void k_ctx_lbl(const float* __restrict__ q, const float* __restrict__ ref,
                          int nref, int k, float* __restrict__ ctx) {
  __shared__ __align__(16) float qs[C];
  __shared__ float ds[256];
  __shared__ int sel[4];
  int row = blockIdx.x, t = threadIdx.x;
  qs[t] = q[(size_t)row * C + t];
  __syncthreads();
  if (t < nref) {
    float s = 0.f;
    const float4* rr = reinterpret_cast<const float4*>(ref + (size_t)t * C);
    const float4* qq = reinterpret_cast<const float4*>(qs);
    #pragma unroll 8
    for (int i = 0; i < 64; ++i) {
      float4 a = rr[i], b = qq[i];
      float dx = a.x - b.x, dy = a.y - b.y, dz = a.z - b.z, dw = a.w - b.w;
      s = fmaf(dx, dx, s); s = fmaf(dy, dy, s);
      s = fmaf(dz, dz, s); s = fmaf(dw, dw, s);
    }
    ds[t] = s;
  } else {
    ds[t] = FLT_MAX;
  }
  __syncthreads();
  if (t < 64) {
    for (int j = 0; j < k; ++j) {
      float m = ds[t]; int mi_ = t;
      #pragma unroll
      for (int o = 64; o < 256; o += 64) {
        float v = ds[t + o];
        if (v < m) { m = v; mi_ = t + o; }
      }
      #pragma unroll
      for (int off = 32; off; off >>= 1) {
        float om = __shfl_down(m, off, 64);
        int oi = __shfl_down(mi_, off, 64);
        if (om < m) { m = om; mi_ = oi; }
      }
      mi_ = __shfl(mi_, 0, 64);
      if (t == 0) sel[j] = mi_;
      ds[mi_] = FLT_MAX;                         // same-address write by all lanes
    }
  }
  __syncthreads();
  float m = -FLT_MAX;
  for (int j = 0; j < k; ++j) m = fmaxf(m, ref[(size_t)sel[j] * C + t]);
  ctx[(size_t)row * C + t] = m - qs[t];
}

// ---------------- fused concat @ W + bias + residual + LayerNorm, 8 rows/block ----------------
__global__ __launch_bounds__(256) void k_out8(
    const float* __restrict__ emb, const float* __restrict__ c0,
    const float* __restrict__ c1, const float* __restrict__ c2,
    const float* __restrict__ W, const float* __restrict__ bias,
    const float* __restrict__ gamma, const float* __restrict__ beta,
    float* __restrict__ out, int nin) {
  __shared__ float x[8][1024];
  __shared__ float red[4][8];
  int row0 = blockIdx.x * 8, t = threadIdx.x;
  float e[8];
  #pragma unroll
  for (int rr = 0; rr < 8; ++rr) {
    size_t o = (size_t)(row0 + rr) * C + t;
    e[rr] = emb[o];
    x[rr][t] = e[rr];
    x[rr][C + t] = c0[o];
    if (c1) x[rr][2 * C + t] = c1[o];
    if (c2) x[rr][3 * C + t] = c2[o];
  }
  __syncthreads();
  float s[8] = {0.f, 0.f, 0.f, 0.f, 0.f, 0.f, 0.f, 0.f};
  for (int i = 0; i < nin; ++i) {
    float wv = W[(size_t)i * C + t];
    #pragma unroll
    for (int rr = 0; rr < 8; ++rr) s[rr] = fmaf(x[rr][i], wv, s[rr]);
  }
  float bv = bias[t];
  float y[8], d[8];
  int wv_ = t >> 6, ln = t & 63;
  #pragma unroll
  for (int rr = 0; rr < 8; ++rr) {
    y[rr] = e[rr] + s[rr] + bv;
    float sum = y[rr];
    #pragma unroll
    for (int off = 32; off; off >>= 1) sum += __shfl_down(sum, off, 64);
    if (ln == 0) red[wv_][rr] = sum;
  }
  __syncthreads();
  float mu[8];
  #pragma unroll
  for (int rr = 0; rr < 8; ++rr)
    mu[rr] = (red[0][rr] + red[1][rr] + red[2][rr] + red[3][rr]) * (1.f / C);
  __syncthreads();
  #pragma unroll
  for (int rr = 0; rr < 8; ++rr) {
    d[rr] = y[rr] - mu[rr];
    float sq = d[rr] * d[rr];
    #pragma unroll
    for (int off = 32; off; off >>= 1) sq += __shfl_down(sq, off, 64);
    if (ln == 0) red[wv_][rr] = sq;
  }
  __syncthreads();
  #pragma unroll
  for (int rr = 0; rr < 8; ++rr) {
    float var = (red[0][rr] + red[1][rr] + red[2][rr] + red[3][rr]) * (1.f / C);
    out[(size_t)(row0 + rr) * C + t] = d[rr] * rsqrtf(var + 1e-5f) * gamma[t] + beta[t];
  }
}

extern "C" void kernel_launch(void* const* d_in, const int* in_sizes, int n_in,
                              void* d_out, int out_size, void* d_ws, size_t ws_size,
                              hipStream_t stream) {
  const float* patch   = (const float*)d_in[0];
  const float* mood_e  = (const float*)d_in[1];
  const float* genre_e = (const float*)d_in[2];
  const float* sub_e   = (const float*)d_in[3];
  const float* Wm  = (const float*)d_in[4];
  const float* bm  = (const float*)d_in[5];
  const float* Wg  = (const float*)d_in[6];
  const float* bg  = (const float*)d_in[7];
  const float* Ws  = (const float*)d_in[8];
  const float* bs_ = (const float*)d_in[9];
  const float* gm  = (const float*)d_in[10];
  const float* bnm = (const float*)d_in[11];
  const float* gg  = (const float*)d_in[12];
  const float* bng = (const float*)d_in[13];
  const float* gs  = (const float*)d_in[14];
  const float* bns = (const float*)d_in[15];

  char* ws = (char*)d_ws;
  size_t off = 0;
  auto alloc = [&](size_t bytes) { void* p = ws + off; off = (off + bytes + 255) & ~(size_t)255; return p; };
  unsigned short* patchB = (unsigned short*)alloc((size_t)N_PATCH * C * 2);   // 51.2 MB
  unsigned short* lblB   = (unsigned short*)alloc((size_t)S_TOT * C * 2);
  float* lblF  = (float*)alloc((size_t)S_TOT * C * 4);
  float* hp2   = (float*)alloc((size_t)N_PATCH * 4);
  float* candS = (float*)alloc((size_t)S_TOT * NCHUNK * KCC * 4);
  int*   candI = (int*)  alloc((size_t)S_TOT * NCHUNK * KCC * 4);
  int*   idx   = (int*)  alloc((size_t)S_TOT * KP * 4);
  float* ctx_m  = (float*)alloc((size_t)64   * C * 4);
  float* ctx_gp = (float*)alloc((size_t)256  * C * 4);
  float* ctx_gm = (float*)alloc((size_t)256  * C * 4);
  float* ctx_sp = (float*)alloc((size_t)1024 * C * 4);
  float* ctx_sm = (float*)alloc((size_t)1024 * C * 4);
  float* ctx_sg = (float*)alloc((size_t)1024 * C * 4);

  float* out_m = (float*)d_out;
  float* out_g = out_m + 64 * C;
  float* out_s = out_g + 256 * C;

  k_prep<<<N_PATCH / 4, 256, 0, stream>>>(patch, patchB, hp2);
  k_preplbl<<<S_TOT, 64, 0, stream>>>(mood_e, genre_e, sub_e, lblB, lblF);
  k_score_mfma<<<dim3(NGRP, NCHUNK), 256, 0, stream>>>((const char*)patchB, (const char*)lblB,
                                                       hp2, candS, candI);
  k_rescore<<<S_TOT, 256, 0, stream>>>(patch, lblF, hp2, candI, idx);
  k_ctx_patch<<<64,   256, 0, stream>>>(patch, mood_e,  idx, 0,   ctx_m);
  k_ctx_patch<<<256,  256, 0, stream>>>(patch, genre_e, idx, 64,  ctx_gp);
  k_ctx_patch<<<1024, 256, 0, stream>>>(patch, sub_e,   idx, 320, ctx_sp);
  k_out8<<<8, 256, 0, stream>>>(mood_e, ctx_m, nullptr, nullptr, Wm, bm, gm, bnm, out_m, 512);
  k_ctx_lbl<<<256, 256, 0, stream>>>(genre_e, out_m, 64, 4, ctx_gm);
  k_out8<<<32, 256, 0, stream>>>(genre_e, ctx_gp, ctx_gm, nullptr, Wg, bg, gg, bng, out_g, 768);
  k_ctx_lbl<<<1024, 256, 0, stream>>>(sub_e, out_m, 64, 3, ctx_sm);
  k_ctx_lbl<<<1024, 256, 0, stream>>>(sub_e, out_g, 256, 4, ctx_sg);
  k_out8<<<128, 256, 0, stream>>>(sub_e, ctx_sp, ctx_sm, ctx_sg, Ws, bs_, gs, bns, out_s, 1024);
}

// Round 4
// 449.251 us; speedup vs baseline: 4.4866x; 1.0895x over previous
//
#include <hip/hip_runtime.h>
#include <float.h>

#define N_PATCH 100000
#define C 256
#define S_TOT 1344
#define LBLK 32
#define NGRP 42
#define NCHUNK 24
#define CHUNKP 4224          // 66 tiles of 64; 24*4224=101376>=100000; tile-aligned
#define PTILE 64
#define KCL 4                // per-lane kept candidates
#define KCC 10               // per-(row,chunk) kept candidates
#define NCAND (NCHUNK*KCC)   // 240
#define NSEL 24              // exact-rescored candidates
#define KP 9

typedef __attribute__((ext_vector_type(8))) short bf16x8;
typedef __attribute__((ext_vector_type(4))) float f32x4;
typedef __attribute__((ext_vector_type(4))) unsigned int u32x4;

#define GLL(gp, lp) __builtin_amdgcn_global_load_lds(                        \
    (__attribute__((address_space(1))) void*)(gp),                           \
    (__attribute__((address_space(3))) void*)(lp), 16, 0, 0)

static __device__ __forceinline__ unsigned short f2bf(float f) {
  unsigned int u = __float_as_uint(f);
  return (unsigned short)((u + 0x7FFFu + ((u >> 16) & 1u)) >> 16);
}

// ---------------- patches: fp32 -> bf16 rows + half squared norms ----------------
__global__ __launch_bounds__(256) void k_prep(const float* __restrict__ patch,
                                              unsigned short* __restrict__ patchB,
                                              float* __restrict__ hp2) {
  int row = (blockIdx.x * blockDim.x + threadIdx.x) >> 6;
  int l = threadIdx.x & 63;
  if (row >= N_PATCH) return;
  float4 p = reinterpret_cast<const float4*>(patch + (size_t)row * C)[l];
  ushort4 h;
  h.x = f2bf(p.x); h.y = f2bf(p.y); h.z = f2bf(p.z); h.w = f2bf(p.w);
  *reinterpret_cast<ushort4*>(patchB + (size_t)row * C + l * 4) = h;
  float s = p.x*p.x + p.y*p.y + p.z*p.z + p.w*p.w;
  #pragma unroll
  for (int off = 32; off; off >>= 1) s += __shfl_down(s, off, 64);
  if (l == 0) hp2[row] = 0.5f * s;
}

// ---------------- labels: concat fp32 + bf16 ----------------
__global__ __launch_bounds__(64) void k_preplbl(const float* __restrict__ m,
                                                const float* __restrict__ g,
                                                const float* __restrict__ s,
                                                unsigned short* __restrict__ lblB,
                                                float* __restrict__ lblF) {
  int row = blockIdx.x, l = threadIdx.x;
  const float* src = (row < 64) ? m + (size_t)row * C
                   : (row < 320) ? g + (size_t)(row - 64) * C
                                 : s + (size_t)(row - 320) * C;
  float4 v = reinterpret_cast<const float4*>(src)[l];
  reinterpret_cast<float4*>(lblF + (size_t)row * C)[l] = v;
  ushort4 h;
  h.x = f2bf(v.x); h.y = f2bf(v.y); h.z = f2bf(v.z); h.w = f2bf(v.w);
  *reinterpret_cast<ushort4*>(lblB + (size_t)row * C + l * 4) = h;
}

// branchless insert of (SV, IV) into sorted-ascending 4-lists
#define BINS(B, I, SV, IV)                                  \
  {                                                         \
    bool c0 = (SV) < B##0, c1 = (SV) < B##1,                \
         c2 = (SV) < B##2, c3 = (SV) < B##3;                \
    I##3 = c2 ? I##2 : (c3 ? (IV) : I##3);                  \
    I##2 = c1 ? I##1 : (c2 ? (IV) : I##2);                  \
    I##1 = c0 ? I##0 : (c1 ? (IV) : I##1);                  \
    I##0 = c0 ? (IV) : I##0;                                \
    B##3 = fminf(B##3, fmaxf(B##2, (SV)));                  \
    B##2 = fminf(B##2, fmaxf(B##1, (SV)));                  \
    B##1 = fminf(B##1, fmaxf(B##0, (SV)));                  \
    B##0 = fminf(B##0, (SV));                               \
  }

// ---------------- MFMA scoring: 32 labels x patch chunk ----------------
// grid 1008 1-D; XCD-local decode: 3 chunks per XCD, chunk slice 2.16MB -> L2-resident.
// Staging: global_load_lds dwordx4, linear LDS dest, inverse-swizzled global source.
__global__ __launch_bounds__(256, 2) void k_score_mfma(
    const char* __restrict__ patchB, const char* __restrict__ lblB,
    const float* __restrict__ hp2,
    float* __restrict__ candS, int* __restrict__ candI) {
  __shared__ char patchS[2][32768];              // double-buffered 64x512B tiles

  const int j = blockIdx.x;
  const int chunk = (j & 7) * 3 + (j >> 3) / NGRP;
  const int grp = (j >> 3) % NGRP;
  const int row0 = grp * LBLK;
  const int p_begin = chunk * CHUNKP;
  const int p_end = min(p_begin + CHUNKP, N_PATCH);
  const int tid = threadIdx.x;
  const int l = tid & 63, w = tid >> 6;

  // stage labels into patchS[1] (reused as buf1 later), swizzled
  char* lblS = patchS[1];
  #pragma unroll
  for (int it = 0; it < 4; ++it) {
    int u = it * 256 + tid;
    int r = u >> 5; int b = (u & 31) << 4;
    u32x4 v = *reinterpret_cast<const u32x4*>(lblB + (((size_t)(row0 + r)) << 9) + b);
    *reinterpret_cast<u32x4*>(lblS + (r << 9) + (b ^ ((r & 7) << 4))) = v;
  }
  __syncthreads();

  // B fragments in registers for the whole block
  const int kq = (l >> 4) << 4;
  bf16x8 bf[2][8];
  #pragma unroll
  for (int nt = 0; nt < 2; ++nt) {
    int r = nt * 16 + (l & 15);
    int xm = (r & 7) << 4;
    #pragma unroll
    for (int ks = 0; ks < 8; ++ks)
      bf[nt][ks] = *reinterpret_cast<const bf16x8*>(lblS + (r << 9) + ((ks * 64 + kq) ^ xm));
  }

  float a0, a1, a2, a3, b0, b1, b2, b3;
  int ia0, ia1, ia2, ia3, ib0, ib1, ib2, ib3;
  a0=a1=a2=a3=b0=b1=b2=b3=FLT_MAX;
  ia0=ia1=ia2=ia3=ib0=ib1=ib2=ib3=0;

  const int ntiles = (p_end - p_begin + PTILE - 1) / PTILE;
  const int prA = (w << 4) + (l & 15);
  const int xmA = (prA & 7) << 4;
  const int psub = (w << 4) + ((l >> 4) << 2);
  const size_t glim = (size_t)N_PATCH * 512 - 16;

  // per-lane inverse-swizzled source offsets for the 8 staging slots
  int srcoff[8];
  #pragma unroll
  for (int i = 0; i < 8; ++i) {
    int u = (w << 13) + (i << 10) + (l << 4);
    srcoff[i] = (u & ~511) | ((u & 511) ^ (((u >> 9) & 7) << 4));
  }

  auto stage = [&](int tile0, int buf) {
    size_t tb = (size_t)tile0 << 9;
    char* dstb = patchS[buf] + (w << 13);
    if (tile0 + PTILE <= N_PATCH) {
      #pragma unroll
      for (int i = 0; i < 8; ++i)
        GLL(patchB + tb + srcoff[i], dstb + (i << 10));
    } else {
      #pragma unroll
      for (int i = 0; i < 8; ++i) {
        size_t a = tb + (size_t)srcoff[i];
        if (a > glim) a = glim;
        GLL(patchB + a, dstb + (i << 10));
      }
    }
  };

  stage(p_begin, 0);
  float4 hcur = *reinterpret_cast<const float4*>(hp2 + min(p_begin + psub, N_PATCH - 4));

  for (int t = 0; t < ntiles; ++t) {
    const int tile0 = p_begin + t * PTILE;
    __syncthreads();                             // buf[t&1] ready; prev reads done
    float4 hnext = hcur;
    if (t + 1 < ntiles) {
      int nt0 = tile0 + PTILE;
      stage(nt0, (t + 1) & 1);                   // in flight across this tile's compute
      hnext = *reinterpret_cast<const float4*>(hp2 + min(nt0 + psub, N_PATCH - 4));
    }

    const char* ab = patchS[t & 1] + (prA << 9);
    f32x4 acc0 = {0.f, 0.f, 0.f, 0.f}, acc1 = {0.f, 0.f, 0.f, 0.f};
    #pragma unroll
    for (int ks = 0; ks < 8; ++ks) {
      bf16x8 a = *reinterpret_cast<const bf16x8*>(ab + ((ks * 64 + kq) ^ xmA));
      acc0 = __builtin_amdgcn_mfma_f32_16x16x32_bf16(a, bf[0][ks], acc0, 0, 0, 0);
      acc1 = __builtin_amdgcn_mfma_f32_16x16x32_bf16(a, bf[1][ks], acc1, 0, 0, 0);
    }

    const int pg0 = tile0 + psub;
    if (tile0 + PTILE <= p_end) {                // fast path (all interior tiles)
      BINS(a, ia, hcur.x - acc0[0], pg0);
      BINS(a, ia, hcur.y - acc0[1], pg0 + 1);
      BINS(a, ia, hcur.z - acc0[2], pg0 + 2);
      BINS(a, ia, hcur.w - acc0[3], pg0 + 3);
      BINS(b, ib, hcur.x - acc1[0], pg0);
      BINS(b, ib, hcur.y - acc1[1], pg0 + 1);
      BINS(b, ib, hcur.z - acc1[2], pg0 + 2);
      BINS(b, ib, hcur.w - acc1[3], pg0 + 3);
    } else {                                     // only last tile of chunk 23
      float s0 = (pg0     < p_end) ? hcur.x - acc0[0] : FLT_MAX;
      float s1 = (pg0 + 1 < p_end) ? hcur.y - acc0[1] : FLT_MAX;
      float s2 = (pg0 + 2 < p_end) ? hcur.z - acc0[2] : FLT_MAX;
      float s3 = (pg0 + 3 < p_end) ? hcur.w - acc0[3] : FLT_MAX;
      float u0 = (pg0     < p_end) ? hcur.x - acc1[0] : FLT_MAX;
      float u1 = (pg0 + 1 < p_end) ? hcur.y - acc1[1] : FLT_MAX;
      float u2 = (pg0 + 2 < p_end) ? hcur.z - acc1[2] : FLT_MAX;
      float u3 = (pg0 + 3 < p_end) ? hcur.w - acc1[3] : FLT_MAX;
      BINS(a, ia, s0, pg0); BINS(a, ia, s1, pg0 + 1);
      BINS(a, ia, s2, pg0 + 2); BINS(a, ia, s3, pg0 + 3);
      BINS(b, ib, u0, pg0); BINS(b, ib, u1, pg0 + 1);
      BINS(b, ib, u2, pg0 + 2); BINS(b, ib, u3, pg0 + 3);
    }
    hcur = hnext;
  }
  __syncthreads();

  // merge 16 lane-subsets per label -> per (row, chunk) top-10
  float* ms = reinterpret_cast<float*>(patchS[0]);         // [32][16][KCL] = 8 KB
  int* mi = reinterpret_cast<int*>(patchS[0] + 8192);
  const int sub = (w << 2) + (l >> 4);
  const int L = l & 15;
  {
    int base0 = (L * 16 + sub) * KCL;
    int base1 = ((L + 16) * 16 + sub) * KCL;
    ms[base0 + 0] = a0; ms[base0 + 1] = a1; ms[base0 + 2] = a2; ms[base0 + 3] = a3;
    mi[base0 + 0] = ia0; mi[base0 + 1] = ia1; mi[base0 + 2] = ia2; mi[base0 + 3] = ia3;
    ms[base1 + 0] = b0; ms[base1 + 1] = b1; ms[base1 + 2] = b2; ms[base1 + 3] = b3;
    mi[base1 + 0] = ib0; mi[base1 + 1] = ib1; mi[base1 + 2] = ib2; mi[base1 + 3] = ib3;
  }
  __syncthreads();
  if (tid < LBLK) {
    float fs[KCC]; int fi[KCC];
    #pragma unroll
    for (int jj = 0; jj < KCC; ++jj) { fs[jj] = FLT_MAX; fi[jj] = 0; }
    for (int q = 0; q < 16 * KCL; ++q) {
      float v = ms[tid * 16 * KCL + q];
      if (v < fs[KCC-1]) {
        fs[KCC-1] = v; fi[KCC-1] = mi[tid * 16 * KCL + q];
        #pragma unroll
        for (int qq = KCC-1; qq >= 1; --qq) {
          if (fs[qq] < fs[qq-1]) {
            float ts = fs[qq]; fs[qq] = fs[qq-1]; fs[qq-1] = ts;
            int ti = fi[qq]; fi[qq] = fi[qq-1]; fi[qq-1] = ti;
          }
        }
      }
    }
    size_t o = ((size_t)(row0 + tid) * NCHUNK + chunk) * KCC;
    #pragma unroll
    for (int jj = 0; jj < KCC; ++jj) { candS[o + jj] = fs[jj]; candI[o + jj] = fi[jj]; }
  }
}

// ---------------- prefilter (rank) + exact fp32 rescore -> top-9 indices ----------------
__global__ __launch_bounds__(256) void k_rescore(
    const float* __restrict__ patchF, const float* __restrict__ lblF,
    const float* __restrict__ hp2, const float* __restrict__ candS,
    const int* __restrict__ candI, int* __restrict__ idxOut) {
  __shared__ float lrow[C];
  __shared__ float ss[NCAND];
  __shared__ int si[NCAND];
  __shared__ int selIdx[NSEL];
  __shared__ float s2[NSEL];
  int row = blockIdx.x, t = threadIdx.x;
  lrow[t] = lblF[(size_t)row * C + t];
  if (t < NCAND) {
    ss[t] = candS[(size_t)row * NCAND + t];
    si[t] = candI[(size_t)row * NCAND + t];
  }
  __syncthreads();
  if (t < NCAND) {                               // all-pairs rank; keep approx-top-24
    float s = ss[t]; int id = si[t];
    int rank = 0;
    for (int q = 0; q < NCAND; ++q) {
      float v = ss[q];
      rank += (v < s) || (v == s && si[q] < id);
    }
    if (rank < NSEL) selIdx[rank] = id;
  }
  __syncthreads();
  {                                              // exact rescore: 8 threads per candidate
    int c = t >> 3, l8 = t & 7;
    if (c < NSEL) {
      const float4* pr = reinterpret_cast<const float4*>(patchF + (size_t)selIdx[c] * C);
      const float4* lr = reinterpret_cast<const float4*>(lrow);
      float d = 0.f;
      #pragma unroll
      for (int i = 0; i < 8; ++i) {
        float4 a = pr[l8 + 8*i], b = lr[l8 + 8*i];
        d = fmaf(a.x, b.x, d); d = fmaf(a.y, b.y, d);
        d = fmaf(a.z, b.z, d); d = fmaf(a.w, b.w, d);
      }
      #pragma unroll
      for (int off = 1; off < 8; off <<= 1) d += __shfl_xor(d, off, 64);
      if (l8 == 0) s2[c] = hp2[selIdx[c]] - d;
    }
  }
  __syncthreads();
  if (t == 0) {
    float fs[KP]; int fi[KP];
    #pragma unroll
    for (int jj = 0; jj < KP; ++jj) { fs[jj] = FLT_MAX; fi[jj] = 0; }
    for (int q = 0; q < NSEL; ++q) {
      float v = s2[q];
      if (v < fs[KP-1]) {
        fs[KP-1] = v; fi[KP-1] = selIdx[q];
        #pragma unroll
        for (int qq = KP-1; qq >= 1; --qq) {
          if (fs[qq] < fs[qq-1]) {
            float ts = fs[qq]; fs[qq] = fs[qq-1]; fs[qq-1] = ts;
            int ti = fi[qq]; fi[qq] = fi[qq-1]; fi[qq-1] = ti;
          }
        }
      }
    }
    #pragma unroll
    for (int jj = 0; jj < KP; ++jj) idxOut[(size_t)row * KP + jj] = fi[jj];
  }
}

// ---------------- ctx from patch: max_j patch[idx_j][c] - label[c] ----------------
__global__ void k_ctx_patch(const float* __restrict__ patch, const float* __restrict__ lbl,
                            const int* __restrict__ idx, int row0, float* __restrict__ ctx) {
  int row = blockIdx.x, c = threadIdx.x;
  const int* id = idx + (size_t)(row0 + row) * KP;
  float m = -FLT_MAX;
  #pragma unroll
  for (int jj = 0; jj < KP; ++jj) m = fmaxf(m, patch[(size_t)id[jj] * C + c]);
  ctx[(size_t)row * C + c] = m - lbl[(size_t)row * C + c];
}

// ---------------- ctx from an updated label set, 4 q-rows per block ----------------
__global__ __launch_bounds__(256) void k_ctx_lbl4(const float* __restrict__ q,
                                                  const float* __restrict__ ref,
                                                  int nref, int k, float* __restrict__ ctx) {
  __shared__ __align__(16) float qs[4][C];
  __shared__ float ds[4][256];
  __shared__ int sel[4][4];
  int row0 = blockIdx.x * 4, t = threadIdx.x;
  int w = t >> 6, ln = t & 63;
  {
    int r = w, c0 = ln << 2;
    *reinterpret_cast<float4*>(&qs[r][c0]) =
        *reinterpret_cast<const float4*>(q + (size_t)(row0 + r) * C + c0);
  }
  __syncthreads();
  float d0 = 0.f, d1 = 0.f, d2 = 0.f, d3 = 0.f;
  if (t < nref) {
    const float4* rr = reinterpret_cast<const float4*>(ref + (size_t)t * C);
    for (int i = 0; i < 64; ++i) {
      float4 a = rr[i];
      float4 v0 = *reinterpret_cast<const float4*>(&qs[0][i << 2]);
      float4 v1 = *reinterpret_cast<const float4*>(&qs[1][i << 2]);
      float4 v2 = *reinterpret_cast<const float4*>(&qs[2][i << 2]);
      float4 v3 = *reinterpret_cast<const float4*>(&qs[3][i << 2]);
      float e;
      e = a.x - v0.x; d0 = fmaf(e, e, d0); e = a.y - v0.y; d0 = fmaf(e, e, d0);
      e = a.z - v0.z; d0 = fmaf(e, e, d0); e = a.w - v0.w; d0 = fmaf(e, e, d0);
      e = a.x - v1.x; d1 = fmaf(e, e, d1); e = a.y - v1.y; d1 = fmaf(e, e, d1);
      e = a.z - v1.z; d1 = fmaf(e, e, d1); e = a.w - v1.w; d1 = fmaf(e, e, d1);
      e = a.x - v2.x; d2 = fmaf(e, e, d2); e = a.y - v2.y; d2 = fmaf(e, e, d2);
      e = a.z - v2.z; d2 = fmaf(e, e, d2); e = a.w - v2.w; d2 = fmaf(e, e, d2);
      e = a.x - v3.x; d3 = fmaf(e, e, d3); e = a.y - v3.y; d3 = fmaf(e, e, d3);
      e = a.z - v3.z; d3 = fmaf(e, e, d3); e = a.w - v3.w; d3 = fmaf(e, e, d3);
    }
  } else { d0 = d1 = d2 = d3 = FLT_MAX; }
  ds[0][t] = d0; ds[1][t] = d1; ds[2][t] = d2; ds[3][t] = d3;
  __syncthreads();
  {                                              // wave w selects top-k for q-row w
    int r = w;
    for (int jj = 0; jj < k; ++jj) {
      float m = ds[r][ln]; int mi_ = ln;
      #pragma unroll
      for (int o = 64; o < 256; o += 64) {
        float v = ds[r][ln + o];
        if (v < m) { m = v; mi_ = ln + o; }
      }
      #pragma unroll
      for (int off = 32; off; off >>= 1) {
        float om = __shfl_down(m, off, 64);
        int oi = __shfl_down(mi_, off, 64);
        if (om < m) { m = om; mi_ = oi; }
      }
      mi_ = __shfl(mi_, 0, 64);
      if (ln == 0) sel[r][jj] = mi_;
      ds[r][mi_] = FLT_MAX;
    }
  }
  __syncthreads();
  #pragma unroll 4
  for (int r = 0; r < 4; ++r) {
    float m = -FLT_MAX;
    for (int jj = 0; jj < k; ++jj) m = fmaxf(m, ref[(size_t)sel[r][jj] * C + t]);
    ctx[(size_t)(row0 + r) * C + t] = m - qs[r][t];
  }
}

// ---------------- projection: y = emb + concat(...) @ W + b  (16 rows x 64 cols/block) ----------------
__global__ __launch_bounds__(256) void k_proj(
    const float* __restrict__ emb, const float* __restrict__ c0,
    const float* __restrict__ c1, const float* __restrict__ c2,
    const float* __restrict__ W, const float* __restrict__ bias,
    float* __restrict__ y, int nin) {
  __shared__ float x[16][1024];
  int row0 = (blockIdx.x >> 2) * 16;
  int cg = (blockIdx.x & 3) << 6;
  int t = threadIdx.x;
  int nv = nin >> 2;
  for (int r = 0; r < 16; ++r) {
    if (t < nv) {
      int seg = t >> 6;
      const float* src = seg == 0 ? emb : seg == 1 ? c0 : seg == 2 ? c1 : c2;
      *reinterpret_cast<float4*>(&x[r][t << 2]) =
          *reinterpret_cast<const float4*>(src + (size_t)(row0 + r) * C + ((t & 63) << 2));
    }
  }
  __syncthreads();
  int col = cg + (t & 63);
  int r0 = (t >> 6) << 2;
  float acc0 = 0.f, acc1 = 0.f, acc2 = 0.f, acc3 = 0.f;
  #pragma unroll 4
  for (int i = 0; i < nin; ++i) {
    float wv = W[(size_t)i * C + col];
    acc0 = fmaf(x[r0 + 0][i], wv, acc0);
    acc1 = fmaf(x[r0 + 1][i], wv, acc1);
    acc2 = fmaf(x[r0 + 2][i], wv, acc2);
    acc3 = fmaf(x[r0 + 3][i], wv, acc3);
  }
  float bv = bias[col];
  y[(size_t)(row0 + r0 + 0) * C + col] = emb[(size_t)(row0 + r0 + 0) * C + col] + acc0 + bv;
  y[(size_t)(row0 + r0 + 1) * C + col] = emb[(size_t)(row0 + r0 + 1) * C + col] + acc1 + bv;
  y[(size_t)(row0 + r0 + 2) * C + col] = emb[(size_t)(row0 + r0 + 2) * C + col] + acc2 + bv;
  y[(size_t)(row0 + r0 + 3) * C + col] = emb[(size_t)(row0 + r0 + 3) * C + col] + acc3 + bv;
}

// ---------------- LayerNorm over 256 cols, one wave per row ----------------
__global__ __launch_bounds__(256) void k_ln(const float* __restrict__ y,
                                            const float* __restrict__ g,
                                            const float* __restrict__ b,
                                            float* __restrict__ out) {
  int row = blockIdx.x * 4 + (threadIdx.x >> 6);
  int ln = threadIdx.x & 63;
  float4 v = reinterpret_cast<const float4*>(y + (size_t)row * C)[ln];
  float s = v.x + v.y + v.z + v.w;
  #pragma unroll
  for (int o = 32; o; o >>= 1) s += __shfl_xor(s, o, 64);
  float mu = s * (1.f / C);
  float4 d = {v.x - mu, v.y - mu, v.z - mu, v.w - mu};
  float q = d.x*d.x + d.y*d.y + d.z*d.z + d.w*d.w;
  #pragma unroll
  for (int o = 32; o; o >>= 1) q += __shfl_xor(q, o, 64);
  float r = rsqrtf(q * (1.f / C) + 1e-5f);
  float4 gg = reinterpret_cast<const float4*>(g)[ln];
  float4 bb = reinterpret_cast<const float4*>(b)[ln];
  float4 o4 = {d.x * r * gg.x + bb.x, d.y * r * gg.y + bb.y,
               d.z * r * gg.z + bb.z, d.w * r * gg.w + bb.w};
  reinterpret_cast<float4*>(out + (size_t)row * C)[ln] = o4;
}

extern "C" void kernel_launch(void* const* d_in, const int* in_sizes, int n_in,
                              void* d_out, int out_size, void* d_ws, size_t ws_size,
                              hipStream_t stream) {
  const float* patch   = (const float*)d_in[0];
  const float* mood_e  = (const float*)d_in[1];
  const float* genre_e = (const float*)d_in[2];
  const float* sub_e   = (const float*)d_in[3];
  const float* Wm  = (const float*)d_in[4];
  const float* bm  = (const float*)d_in[5];
  const float* Wg  = (const float*)d_in[6];
  const float* bg  = (const float*)d_in[7];
  const float* Ws  = (const float*)d_in[8];
  const float* bs_ = (const float*)d_in[9];
  const float* gm  = (const float*)d_in[10];
  const float* bnm = (const float*)d_in[11];
  const float* gg  = (const float*)d_in[12];
  const float* bng = (const float*)d_in[13];
  const float* gs  = (const float*)d_in[14];
  const float* bns = (const float*)d_in[15];

  char* ws = (char*)d_ws;
  size_t off = 0;
  auto alloc = [&](size_t bytes) { void* p = ws + off; off = (off + bytes + 255) & ~(size_t)255; return p; };
  unsigned short* patchB = (unsigned short*)alloc((size_t)N_PATCH * C * 2);   // 51.2 MB
  unsigned short* lblB   = (unsigned short*)alloc((size_t)S_TOT * C * 2);
  float* lblF  = (float*)alloc((size_t)S_TOT * C * 4);
  float* hp2   = (float*)alloc((size_t)N_PATCH * 4);
  float* candS = (float*)alloc((size_t)S_TOT * NCAND * 4);
  int*   candI = (int*)  alloc((size_t)S_TOT * NCAND * 4);
  int*   idx   = (int*)  alloc((size_t)S_TOT * KP * 4);
  float* ctx_m  = (float*)alloc((size_t)64   * C * 4);
  float* ctx_gp = (float*)alloc((size_t)256  * C * 4);
  float* ctx_gm = (float*)alloc((size_t)256  * C * 4);
  float* ctx_sp = (float*)alloc((size_t)1024 * C * 4);
  float* ctx_sm = (float*)alloc((size_t)1024 * C * 4);
  float* ctx_sg = (float*)alloc((size_t)1024 * C * 4);
  float* yb     = (float*)alloc((size_t)1024 * C * 4);

  float* out_m = (float*)d_out;
  float* out_g = out_m + 64 * C;
  float* out_s = out_g + 256 * C;

  k_prep<<<N_PATCH / 4, 256, 0, stream>>>(patch, patchB, hp2);
  k_preplbl<<<S_TOT, 64, 0, stream>>>(mood_e, genre_e, sub_e, lblB, lblF);
  k_score_mfma<<<NGRP * NCHUNK, 256, 0, stream>>>((const char*)patchB, (const char*)lblB,
                                                  hp2, candS, candI);
  k_rescore<<<S_TOT, 256, 0, stream>>>(patch, lblF, hp2, candS, candI, idx);
  k_ctx_patch<<<64,   256, 0, stream>>>(patch, mood_e,  idx, 0,   ctx_m);
  k_ctx_patch<<<256,  256, 0, stream>>>(patch, genre_e, idx, 64,  ctx_gp);
  k_ctx_patch<<<1024, 256, 0, stream>>>(patch, sub_e,   idx, 320, ctx_sp);

  k_proj<<<16, 256, 0, stream>>>(mood_e, ctx_m, nullptr, nullptr, Wm, bm, yb, 512);
  k_ln<<<16, 256, 0, stream>>>(yb, gm, bnm, out_m);

  k_ctx_lbl4<<<64, 256, 0, stream>>>(genre_e, out_m, 64, 4, ctx_gm);
  k_proj<<<64, 256, 0, stream>>>(genre_e, ctx_gp, ctx_gm, nullptr, Wg, bg, yb, 768);
  k_ln<<<64, 256, 0, stream>>>(yb, gg, bng, out_g);

  k_ctx_lbl4<<<256, 256, 0, stream>>>(sub_e, out_m, 64, 3, ctx_sm);
  k_ctx_lbl4<<<256, 256, 0, stream>>>(sub_e, out_g, 256, 4, ctx_sg);
  k_proj<<<256, 256, 0, stream>>>(sub_e, ctx_sp, ctx_sm, ctx_sg, Ws, bs_, yb, 1024);
  k_ln<<<256, 256, 0, stream>>>(yb, gs, bns, out_s);
}

// Round 5
// 361.649 us; speedup vs baseline: 5.5734x; 1.2422x over previous
//
#include <hip/hip_runtime.h>
#include <float.h>

#define N_PATCH 100000
#define C 256
#define S_TOT 1344
#define LBLK 32
#define NGRP 42
#define NCHUNK 24
#define CHUNKP 4224          // 66 tiles of 64; tile-aligned; 24*4224 >= 100000
#define PTILE 64
#define KCC 10               // per-(row,chunk) kept candidates
#define NCAND (NCHUNK*KCC)   // 240
#define NSEL 24              // exact-rescored candidates
#define KP 9
#define SMASK 0xFFFFE000u    // keep sign+exp+10 mantissa bits; low 13 bits = local idx
#define KINIT 0x7F7FFFFFu    // FLT_MAX pattern: largest finite-positive key

typedef __attribute__((ext_vector_type(8))) short bf16x8;
typedef __attribute__((ext_vector_type(4))) float f32x4;
typedef __attribute__((ext_vector_type(4))) unsigned int u32x4;

#define GLL(gp, lp) __builtin_amdgcn_global_load_lds(                        \
    (__attribute__((address_space(1))) void*)(gp),                           \
    (__attribute__((address_space(3))) void*)(lp), 16, 0, 0)

static __device__ __forceinline__ unsigned short f2bf(float f) {
  unsigned int u = __float_as_uint(f);
  return (unsigned short)((u + 0x7FFFu + ((u >> 16) & 1u)) >> 16);
}

// u32 sorted-3 min/max network insert (score-packed keys)
#define KNET3(K0, K1, K2, KV)                               \
  { unsigned int _kv = (KV);                                \
    K2 = min(K2, max(K1, _kv));                             \
    K1 = min(K1, max(K0, _kv));                             \
    K0 = min(K0, _kv); }

// ---------------- fused prep: patches (bf16 + biased half-norm) and labels ----------------
__global__ __launch_bounds__(256) void k_prep(
    const float* __restrict__ patch, const float* __restrict__ me,
    const float* __restrict__ ge, const float* __restrict__ se,
    unsigned short* __restrict__ patchB, unsigned short* __restrict__ lblB,
    float* __restrict__ lblF, float* __restrict__ hp2) {
  int bid = blockIdx.x;
  int w = threadIdx.x >> 6, l = threadIdx.x & 63;
  if (bid < N_PATCH / 4) {
    int row = bid * 4 + w;
    float4 p = reinterpret_cast<const float4*>(patch + (size_t)row * C)[l];
    ushort4 h;
    h.x = f2bf(p.x); h.y = f2bf(p.y); h.z = f2bf(p.z); h.w = f2bf(p.w);
    *reinterpret_cast<ushort4*>(patchB + (size_t)row * C + l * 4) = h;
    float s = p.x*p.x + p.y*p.y + p.z*p.z + p.w*p.w;
    #pragma unroll
    for (int off = 32; off; off >>= 1) s += __shfl_down(s, off, 64);
    if (l == 0) hp2[row] = 0.5f * s + 512.0f;          // biased: always > dot
  } else {
    int row = (bid - N_PATCH / 4) * 4 + w;             // 0..1343
    const float* src = (row < 64) ? me + (size_t)row * C
                     : (row < 320) ? ge + (size_t)(row - 64) * C
                                   : se + (size_t)(row - 320) * C;
    float4 v = reinterpret_cast<const float4*>(src)[l];
    reinterpret_cast<float4*>(lblF + (size_t)row * C)[l] = v;
    ushort4 h;
    h.x = f2bf(v.x); h.y = f2bf(v.y); h.z = f2bf(v.z); h.w = f2bf(v.w);
    *reinterpret_cast<ushort4*>(lblB + (size_t)row * C + l * 4) = h;
  }
}

// ---------------- MFMA scoring: 32 labels x patch chunk, packed-key top-3/lane ----------------
__global__ __launch_bounds__(256, 2) void k_score_mfma(
    const char* __restrict__ patchB, const char* __restrict__ lblB,
    const float* __restrict__ hp2,
    float* __restrict__ candS, int* __restrict__ candI) {
  __shared__ char patchS[2][32768];                    // double-buffered 64x512B tiles

  const int j = blockIdx.x;
  const int chunk = (j & 7) * 3 + (j >> 3) / NGRP;     // XCD-local chunks
  const int grp = (j >> 3) % NGRP;
  const int row0 = grp * LBLK;
  const int p_begin = chunk * CHUNKP;
  const int p_end = min(p_begin + CHUNKP, N_PATCH);
  const int tid = threadIdx.x;
  const int l = tid & 63, w = tid >> 6;

  // stage labels into patchS[1] (reclaimed as buf1 after frags read), swizzled
  char* lblS = patchS[1];
  #pragma unroll
  for (int it = 0; it < 4; ++it) {
    int u = it * 256 + tid;
    int r = u >> 5; int b = (u & 31) << 4;
    u32x4 v = *reinterpret_cast<const u32x4*>(lblB + (((size_t)(row0 + r)) << 9) + b);
    *reinterpret_cast<u32x4*>(lblS + (r << 9) + (b ^ ((r & 7) << 4))) = v;
  }
  __syncthreads();

  const int kq = (l >> 4) << 4;
  bf16x8 bf[2][8];
  #pragma unroll
  for (int nt = 0; nt < 2; ++nt) {
    int r = nt * 16 + (l & 15);
    int xm = (r & 7) << 4;
    #pragma unroll
    for (int ks = 0; ks < 8; ++ks)
      bf[nt][ks] = *reinterpret_cast<const bf16x8*>(lblS + (r << 9) + ((ks * 64 + kq) ^ xm));
  }

  unsigned int a0k = KINIT, a1k = KINIT, a2k = KINIT;
  unsigned int b0k = KINIT, b1k = KINIT, b2k = KINIT;

  const int ntiles = (p_end - p_begin + PTILE - 1) / PTILE;
  const int prA = (w << 4) + (l & 15);
  const int xmA = (prA & 7) << 4;
  const int psub = (w << 4) + ((l >> 4) << 2);
  const size_t glim = (size_t)N_PATCH * 512 - 16;

  int srcoff[8];
  #pragma unroll
  for (int i = 0; i < 8; ++i) {
    int u = (w << 13) + (i << 10) + (l << 4);
    srcoff[i] = (u & ~511) | ((u & 511) ^ (((u >> 9) & 7) << 4));
  }

  auto stage = [&](int tile0, int buf) {
    size_t tb = (size_t)tile0 << 9;
    char* dstb = patchS[buf] + (w << 13);
    if (tile0 + PTILE <= N_PATCH) {
      #pragma unroll
      for (int i = 0; i < 8; ++i)
        GLL(patchB + tb + srcoff[i], dstb + (i << 10));
    } else {
      #pragma unroll
      for (int i = 0; i < 8; ++i) {
        size_t a = tb + (size_t)srcoff[i];
        if (a > glim) a = glim;
        GLL(patchB + a, dstb + (i << 10));
      }
    }
  };

  stage(p_begin, 0);
  float4 hcur = *reinterpret_cast<const float4*>(hp2 + min(p_begin + psub, N_PATCH - 4));
  unsigned int lidx = (unsigned int)psub;              // local idx base; psub % 4 == 0

  for (int t = 0; t < ntiles; ++t) {
    const int tile0 = p_begin + t * PTILE;
    __syncthreads();                                   // buf[t&1] ready; prev reads done
    float4 hnext = hcur;
    if (t + 1 < ntiles) {
      int nt0 = tile0 + PTILE;
      stage(nt0, (t + 1) & 1);                         // in flight across this compute
      hnext = *reinterpret_cast<const float4*>(hp2 + min(nt0 + psub, N_PATCH - 4));
    }

    const char* ab = patchS[t & 1] + (prA << 9);
    f32x4 acc0 = {0.f, 0.f, 0.f, 0.f}, acc1 = {0.f, 0.f, 0.f, 0.f};
    #pragma unroll
    for (int ks = 0; ks < 8; ++ks) {
      bf16x8 a = *reinterpret_cast<const bf16x8*>(ab + ((ks * 64 + kq) ^ xmA));
      acc0 = __builtin_amdgcn_mfma_f32_16x16x32_bf16(a, bf[0][ks], acc0, 0, 0, 0);
      acc1 = __builtin_amdgcn_mfma_f32_16x16x32_bf16(a, bf[1][ks], acc1, 0, 0, 0);
    }

    unsigned int l1 = lidx | 1u, l2 = lidx | 2u, l3 = lidx | 3u;
    if (tile0 + PTILE <= p_end) {                      // interior fast path
      KNET3(a0k, a1k, a2k, (__float_as_uint(hcur.x - acc0[0]) & SMASK) | lidx);
      KNET3(a0k, a1k, a2k, (__float_as_uint(hcur.y - acc0[1]) & SMASK) | l1);
      KNET3(a0k, a1k, a2k, (__float_as_uint(hcur.z - acc0[2]) & SMASK) | l2);
      KNET3(a0k, a1k, a2k, (__float_as_uint(hcur.w - acc0[3]) & SMASK) | l3);
      KNET3(b0k, b1k, b2k, (__float_as_uint(hcur.x - acc1[0]) & SMASK) | lidx);
      KNET3(b0k, b1k, b2k, (__float_as_uint(hcur.y - acc1[1]) & SMASK) | l1);
      KNET3(b0k, b1k, b2k, (__float_as_uint(hcur.z - acc1[2]) & SMASK) | l2);
      KNET3(b0k, b1k, b2k, (__float_as_uint(hcur.w - acc1[3]) & SMASK) | l3);
    } else {                                           // only last tile of chunk 23
      const int pg0 = tile0 + psub;
      unsigned int k0 = (pg0     < p_end) ? ((__float_as_uint(hcur.x - acc0[0]) & SMASK) | lidx) : KINIT;
      unsigned int k1 = (pg0 + 1 < p_end) ? ((__float_as_uint(hcur.y - acc0[1]) & SMASK) | l1) : KINIT;
      unsigned int k2 = (pg0 + 2 < p_end) ? ((__float_as_uint(hcur.z - acc0[2]) & SMASK) | l2) : KINIT;
      unsigned int k3 = (pg0 + 3 < p_end) ? ((__float_as_uint(hcur.w - acc0[3]) & SMASK) | l3) : KINIT;
      unsigned int m0 = (pg0     < p_end) ? ((__float_as_uint(hcur.x - acc1[0]) & SMASK) | lidx) : KINIT;
      unsigned int m1 = (pg0 + 1 < p_end) ? ((__float_as_uint(hcur.y - acc1[1]) & SMASK) | l1) : KINIT;
      unsigned int m2 = (pg0 + 2 < p_end) ? ((__float_as_uint(hcur.z - acc1[2]) & SMASK) | l2) : KINIT;
      unsigned int m3 = (pg0 + 3 < p_end) ? ((__float_as_uint(hcur.w - acc1[3]) & SMASK) | l3) : KINIT;
      KNET3(a0k, a1k, a2k, k0); KNET3(a0k, a1k, a2k, k1);
      KNET3(a0k, a1k, a2k, k2); KNET3(a0k, a1k, a2k, k3);
      KNET3(b0k, b1k, b2k, m0); KNET3(b0k, b1k, b2k, m1);
      KNET3(b0k, b1k, b2k, m2); KNET3(b0k, b1k, b2k, m3);
    }
    lidx += 64u;
    hcur = hnext;
  }
  __syncthreads();

  // merge 16 lane-subsets x 3 keys per label -> per (row, chunk) top-10
  unsigned int* ks_ = reinterpret_cast<unsigned int*>(patchS[0]);  // [32][16][3] u32
  const int sub = (w << 2) + (l >> 4);
  const int L = l & 15;
  {
    int base0 = (L * 16 + sub) * 3;
    int base1 = ((L + 16) * 16 + sub) * 3;
    ks_[base0 + 0] = a0k; ks_[base0 + 1] = a1k; ks_[base0 + 2] = a2k;
    ks_[base1 + 0] = b0k; ks_[base1 + 1] = b1k; ks_[base1 + 2] = b2k;
  }
  __syncthreads();
  if (tid < LBLK) {
    unsigned int fk[KCC];
    #pragma unroll
    for (int jj = 0; jj < KCC; ++jj) fk[jj] = KINIT;
    for (int q = 0; q < 48; ++q) {
      unsigned int v = ks_[tid * 48 + q];
      if (v < fk[KCC-1]) {
        fk[KCC-1] = v;
        #pragma unroll
        for (int qq = KCC-1; qq >= 1; --qq) {
          if (fk[qq] < fk[qq-1]) {
            unsigned int tv = fk[qq]; fk[qq] = fk[qq-1]; fk[qq-1] = tv;
          }
        }
      }
    }
    size_t o = ((size_t)(row0 + tid) * NCHUNK + chunk) * KCC;
    #pragma unroll
    for (int jj = 0; jj < KCC; ++jj) {
      candS[o + jj] = __uint_as_float(fk[jj] & SMASK);
      candI[o + jj] = p_begin + (int)(fk[jj] & 0x1FFFu);
    }
  }
}

// ---------------- fused: prefilter + exact fp32 rescore + top-9 + ctx_patch ----------------
__global__ __launch_bounds__(256) void k_rescore_ctx(
    const float* __restrict__ patchF, const float* __restrict__ lblF,
    const float* __restrict__ hp2, const float* __restrict__ candS,
    const int* __restrict__ candI,
    float* __restrict__ ctx_m, float* __restrict__ ctx_gp, float* __restrict__ ctx_sp) {
  __shared__ float lrow[C];
  __shared__ float ss[NCAND];
  __shared__ int si[NCAND];
  __shared__ int selIdx[NSEL];
  __shared__ float s2[NSEL];
  __shared__ int top[KP];
  int row = blockIdx.x, t = threadIdx.x;
  lrow[t] = lblF[(size_t)row * C + t];
  if (t < NCAND) {
    ss[t] = candS[(size_t)row * NCAND + t];
    si[t] = candI[(size_t)row * NCAND + t];
  }
  __syncthreads();
  if (t < NCAND) {                                     // all-pairs rank; keep approx-top-24
    float s = ss[t]; int id = si[t];
    int rank = 0;
    for (int q = 0; q < NCAND; ++q) {
      float v = ss[q];
      rank += (v < s) || (v == s && si[q] < id);
    }
    if (rank < NSEL) selIdx[rank] = id;
  }
  __syncthreads();
  {                                                    // exact rescore: 8 threads/candidate
    int c = t >> 3, l8 = t & 7;
    if (c < NSEL) {
      const float4* pr = reinterpret_cast<const float4*>(patchF + (size_t)selIdx[c] * C);
      const float4* lr = reinterpret_cast<const float4*>(lrow);
      float dx = 0.f, dy = 0.f, dz = 0.f, dw = 0.f;
      #pragma unroll
      for (int i = 0; i < 8; ++i) {
        float4 a = pr[l8 + 8*i], b = lr[l8 + 8*i];
        dx = fmaf(a.x, b.x, dx); dy = fmaf(a.y, b.y, dy);
        dz = fmaf(a.z, b.z, dz); dw = fmaf(a.w, b.w, dw);
      }
      float d = (dx + dy) + (dz + dw);
      #pragma unroll
      for (int off = 1; off < 8; off <<= 1) d += __shfl_xor(d, off, 64);
      if (l8 == 0) s2[c] = hp2[selIdx[c]] - d;         // biased, consistent ranking
    }
  }
  __syncthreads();
  if (t == 0) {
    float fs[KP]; int fi[KP];
    #pragma unroll
    for (int jj = 0; jj < KP; ++jj) { fs[jj] = FLT_MAX; fi[jj] = 0; }
    for (int q = 0; q < NSEL; ++q) {
      float v = s2[q];
      if (v < fs[KP-1]) {
        fs[KP-1] = v; fi[KP-1] = selIdx[q];
        #pragma unroll
        for (int qq = KP-1; qq >= 1; --qq) {
          if (fs[qq] < fs[qq-1]) {
            float ts = fs[qq]; fs[qq] = fs[qq-1]; fs[qq-1] = ts;
            int ti = fi[qq]; fi[qq] = fi[qq-1]; fi[qq-1] = ti;
          }
        }
      }
    }
    #pragma unroll
    for (int jj = 0; jj < KP; ++jj) top[jj] = fi[jj];
  }
  __syncthreads();
  float m = -FLT_MAX;
  #pragma unroll
  for (int jj = 0; jj < KP; ++jj)
    m = fmaxf(m, patchF[(size_t)top[jj] * C + t]);     // rows L1/L2-hot from rescore
  float* dst; int rr;
  if (row < 64)       { dst = ctx_m;  rr = row; }
  else if (row < 320) { dst = ctx_gp; rr = row - 64; }
  else                { dst = ctx_sp; rr = row - 320; }
  dst[(size_t)rr * C + t] = m - lrow[t];
}

// ---------------- device helper: dists of 4 q-rows (in qs) to nref rows of ref ----------------
static __device__ __forceinline__ void ctx_from_refs(
    const float (&qs)[4][C], float (&ds)[4][256], int (&sel)[4][4],
    const float* __restrict__ ref, int nref, int k,
    float* __restrict__ ctx, int row0, int t) {
  int w = t >> 6, ln = t & 63;
  int nk = nref >> 6;                                  // 1 or 4
  for (int kk = 0; kk < nk; ++kk) {                    // thread -> (q=w, ref=ln+64kk)
    int ri = ln + (kk << 6);
    const float4* rr = reinterpret_cast<const float4*>(ref + (size_t)ri * C);
    const float4* qq = reinterpret_cast<const float4*>(qs[w]);
    float dx = 0.f, dy = 0.f, dz = 0.f, dw = 0.f;
    #pragma unroll 8
    for (int i = 0; i < 64; ++i) {
      float4 a = rr[i], b = qq[i];
      float e;
      e = a.x - b.x; dx = fmaf(e, e, dx);
      e = a.y - b.y; dy = fmaf(e, e, dy);
      e = a.z - b.z; dz = fmaf(e, e, dz);
      e = a.w - b.w; dw = fmaf(e, e, dw);
    }
    ds[w][ri] = (dx + dy) + (dz + dw);
  }
  __syncthreads();
  {                                                    // wave w: top-k for q-row w
    for (int jj = 0; jj < k; ++jj) {
      float m = ds[w][ln]; int mi_ = ln;
      for (int o = 64; o < nref; o += 64) {
        float v = ds[w][ln + o];
        if (v < m) { m = v; mi_ = ln + o; }
      }
      #pragma unroll
      for (int off = 32; off; off >>= 1) {
        float om = __shfl_down(m, off, 64);
        int oi = __shfl_down(mi_, off, 64);
        if (om < m) { m = om; mi_ = oi; }
      }
      mi_ = __shfl(mi_, 0, 64);
      if (ln == 0) sel[w][jj] = mi_;
      ds[w][mi_] = FLT_MAX;
    }
  }
  __syncthreads();
  #pragma unroll 4
  for (int r = 0; r < 4; ++r) {
    float m = -FLT_MAX;
    for (int jj = 0; jj < k; ++jj) m = fmaxf(m, ref[(size_t)sel[r][jj] * C + t]);
    ctx[(size_t)(row0 + r) * C + t] = m - qs[r][t];
  }
}

// ---------------- ctx from one updated label set (4 q-rows/block) ----------------
__global__ __launch_bounds__(256) void k_ctx_lbl4(const float* __restrict__ q,
                                                  const float* __restrict__ ref,
                                                  int nref, int k, float* __restrict__ ctx) {
  __shared__ __align__(16) float qs[4][C];
  __shared__ float ds[4][256];
  __shared__ int sel[4][4];
  int row0 = blockIdx.x * 4, t = threadIdx.x, w = t >> 6, ln = t & 63;
  *reinterpret_cast<float4*>(&qs[w][ln << 2]) =
      *reinterpret_cast<const float4*>(q + (size_t)(row0 + w) * C + (ln << 2));
  __syncthreads();
  ctx_from_refs(qs, ds, sel, ref, nref, k, ctx, row0, t);
}

// ---------------- sub: both label-ctx in one launch (shared q staging) ----------------
__global__ __launch_bounds__(256) void k_ctx_sub2(const float* __restrict__ se,
                                                  const float* __restrict__ out_m,
                                                  const float* __restrict__ out_g,
                                                  float* __restrict__ ctx_sm,
                                                  float* __restrict__ ctx_sg) {
  __shared__ __align__(16) float qs[4][C];
  __shared__ float ds[4][256];
  __shared__ int sel[4][4];
  int row0 = blockIdx.x * 4, t = threadIdx.x, w = t >> 6, ln = t & 63;
  *reinterpret_cast<float4*>(&qs[w][ln << 2]) =
      *reinterpret_cast<const float4*>(se + (size_t)(row0 + w) * C + (ln << 2));
  __syncthreads();
  ctx_from_refs(qs, ds, sel, out_m, 64, 3, ctx_sm, row0, t);
  __syncthreads();
  ctx_from_refs(qs, ds, sel, out_g, 256, 4, ctx_sg, row0, t);
}

// ---------------- fused concat @ W + bias + residual + LayerNorm, 8 rows/block ----------------
__global__ __launch_bounds__(256) void k_out8(
    const float* __restrict__ emb, const float* __restrict__ c0,
    const float* __restrict__ c1, const float* __restrict__ c2,
    const float* __restrict__ W, const float* __restrict__ bias,
    const float* __restrict__ gamma, const float* __restrict__ beta,
    float* __restrict__ out, int nin) {
  __shared__ float x[8][1024];
  __shared__ float red[4][8];
  int row0 = blockIdx.x * 8, t = threadIdx.x;
  float e[8];
  #pragma unroll
  for (int rr = 0; rr < 8; ++rr) {
    size_t o = (size_t)(row0 + rr) * C + t;
    e[rr] = emb[o];
    x[rr][t] = e[rr];
    x[rr][C + t] = c0[o];
    if (c1) x[rr][2 * C + t] = c1[o];
    if (c2) x[rr][3 * C + t] = c2[o];
  }
  __syncthreads();
  float s[8] = {0.f, 0.f, 0.f, 0.f, 0.f, 0.f, 0.f, 0.f};
  for (int i = 0; i < nin; ++i) {
    float wv = W[(size_t)i * C + t];
    #pragma unroll
    for (int rr = 0; rr < 8; ++rr) s[rr] = fmaf(x[rr][i], wv, s[rr]);
  }
  float bv = bias[t];
  float y[8], d[8];
  int wv_ = t >> 6, ln = t & 63;
  #pragma unroll
  for (int rr = 0; rr < 8; ++rr) {
    y[rr] = e[rr] + s[rr] + bv;
    float sum = y[rr];
    #pragma unroll
    for (int off = 32; off; off >>= 1) sum += __shfl_down(sum, off, 64);
    if (ln == 0) red[wv_][rr] = sum;
  }
  __syncthreads();
  float mu[8];
  #pragma unroll
  for (int rr = 0; rr < 8; ++rr)
    mu[rr] = (red[0][rr] + red[1][rr] + red[2][rr] + red[3][rr]) * (1.f / C);
  __syncthreads();
  #pragma unroll
  for (int rr = 0; rr < 8; ++rr) {
    d[rr] = y[rr] - mu[rr];
    float sq = d[rr] * d[rr];
    #pragma unroll
    for (int off = 32; off; off >>= 1) sq += __shfl_down(sq, off, 64);
    if (ln == 0) red[wv_][rr] = sq;
  }
  __syncthreads();
  #pragma unroll
  for (int rr = 0; rr < 8; ++rr) {
    float var = (red[0][rr] + red[1][rr] + red[2][rr] + red[3][rr]) * (1.f / C);
    out[(size_t)(row0 + rr) * C + t] = d[rr] * rsqrtf(var + 1e-5f) * gamma[t] + beta[t];
  }
}

extern "C" void kernel_launch(void* const* d_in, const int* in_sizes, int n_in,
                              void* d_out, int out_size, void* d_ws, size_t ws_size,
                              hipStream_t stream) {
  const float* patch   = (const float*)d_in[0];
  const float* mood_e  = (const float*)d_in[1];
  const float* genre_e = (const float*)d_in[2];
  const float* sub_e   = (const float*)d_in[3];
  const float* Wm  = (const float*)d_in[4];
  const float* bm  = (const float*)d_in[5];
  const float* Wg  = (const float*)d_in[6];
  const float* bg  = (const float*)d_in[7];
  const float* Ws  = (const float*)d_in[8];
  const float* bs_ = (const float*)d_in[9];
  const float* gm  = (const float*)d_in[10];
  const float* bnm = (const float*)d_in[11];
  const float* gg  = (const float*)d_in[12];
  const float* bng = (const float*)d_in[13];
  const float* gs  = (const float*)d_in[14];
  const float* bns = (const float*)d_in[15];

  char* ws = (char*)d_ws;
  size_t off = 0;
  auto alloc = [&](size_t bytes) { void* p = ws + off; off = (off + bytes + 255) & ~(size_t)255; return p; };
  unsigned short* patchB = (unsigned short*)alloc((size_t)N_PATCH * C * 2);   // 51.2 MB
  unsigned short* lblB   = (unsigned short*)alloc((size_t)S_TOT * C * 2);
  float* lblF  = (float*)alloc((size_t)S_TOT * C * 4);
  float* hp2   = (float*)alloc((size_t)N_PATCH * 4);
  float* candS = (float*)alloc((size_t)S_TOT * NCAND * 4);
  int*   candI = (int*)  alloc((size_t)S_TOT * NCAND * 4);
  float* ctx_m  = (float*)alloc((size_t)64   * C * 4);
  float* ctx_gp = (float*)alloc((size_t)256  * C * 4);
  float* ctx_gm = (float*)alloc((size_t)256  * C * 4);
  float* ctx_sp = (float*)alloc((size_t)1024 * C * 4);
  float* ctx_sm = (float*)alloc((size_t)1024 * C * 4);
  float* ctx_sg = (float*)alloc((size_t)1024 * C * 4);

  float* out_m = (float*)d_out;
  float* out_g = out_m + 64 * C;
  float* out_s = out_g + 256 * C;

  k_prep<<<N_PATCH / 4 + S_TOT / 4, 256, 0, stream>>>(patch, mood_e, genre_e, sub_e,
                                                      patchB, lblB, lblF, hp2);
  k_score_mfma<<<NGRP * NCHUNK, 256, 0, stream>>>((const char*)patchB, (const char*)lblB,
                                                  hp2, candS, candI);
  k_rescore_ctx<<<S_TOT, 256, 0, stream>>>(patch, lblF, hp2, candS, candI,
                                           ctx_m, ctx_gp, ctx_sp);
  k_out8<<<8, 256, 0, stream>>>(mood_e, ctx_m, nullptr, nullptr, Wm, bm, gm, bnm, out_m, 512);
  k_ctx_lbl4<<<64, 256, 0, stream>>>(genre_e, out_m, 64, 4, ctx_gm);
  k_out8<<<32, 256, 0, stream>>>(genre_e, ctx_gp, ctx_gm, nullptr, Wg, bg, gg, bng, out_g, 768);
  k_ctx_sub2<<<256, 256, 0, stream>>>(sub_e, out_m, out_g, ctx_sm, ctx_sg);
  k_out8<<<128, 256, 0, stream>>>(sub_e, ctx_sp, ctx_sm, ctx_sg, Ws, bs_, gs, bns, out_s, 1024);
}

// Round 6
// 291.023 us; speedup vs baseline: 6.9259x; 1.2427x over previous
//
#include <hip/hip_runtime.h>
#include <float.h>

#define N_PATCH 100000
#define C 256
#define S_TOT 1344
#define LBLK 32
#define NGRP 42
#define NCHUNK 24
#define CHUNKP 4224          // 66 tiles of 64; tile-aligned; 24*4224 >= 100000
#define PTILE 64
#define KCC 10               // per-(row,chunk) kept candidates
#define NCAND (NCHUNK*KCC)   // 240
#define NSEL 24              // exact-rescored candidates
#define KP 9
#define SMASK 0xFFFFE000u    // keep sign+exp+10 mantissa bits; low 13 bits = local idx
#define KINIT 0x7F7FFFFFu    // FLT_MAX pattern: largest finite-positive key

typedef __attribute__((ext_vector_type(8))) short bf16x8;
typedef __attribute__((ext_vector_type(4))) float f32x4;
typedef __attribute__((ext_vector_type(4))) unsigned int u32x4;

#define GLL(gp, lp) __builtin_amdgcn_global_load_lds(                        \
    (__attribute__((address_space(1))) void*)(gp),                           \
    (__attribute__((address_space(3))) void*)(lp), 16, 0, 0)

static __device__ __forceinline__ unsigned short f2bf(float f) {
  unsigned int u = __float_as_uint(f);
  return (unsigned short)((u + 0x7FFFu + ((u >> 16) & 1u)) >> 16);
}

// u32 sorted-3 min/max network insert (score-packed keys)
#define KNET3(K0, K1, K2, KV)                               \
  { unsigned int _kv = (KV);                                \
    K2 = min(K2, max(K1, _kv));                             \
    K1 = min(K1, max(K0, _kv));                             \
    K0 = min(K0, _kv); }

// ---------------- fused prep: patches (bf16 + biased half-norm) and labels ----------------
__global__ __launch_bounds__(256) void k_prep(
    const float* __restrict__ patch, const float* __restrict__ me,
    const float* __restrict__ ge, const float* __restrict__ se,
    unsigned short* __restrict__ patchB, unsigned short* __restrict__ lblB,
    float* __restrict__ hp2) {
  int bid = blockIdx.x;
  int w = threadIdx.x >> 6, l = threadIdx.x & 63;
  if (bid < N_PATCH / 4) {
    int row = bid * 4 + w;
    float4 p = reinterpret_cast<const float4*>(patch + (size_t)row * C)[l];
    ushort4 h;
    h.x = f2bf(p.x); h.y = f2bf(p.y); h.z = f2bf(p.z); h.w = f2bf(p.w);
    *reinterpret_cast<ushort4*>(patchB + (size_t)row * C + l * 4) = h;
    float s = p.x*p.x + p.y*p.y + p.z*p.z + p.w*p.w;
    #pragma unroll
    for (int off = 32; off; off >>= 1) s += __shfl_down(s, off, 64);
    if (l == 0) hp2[row] = 0.5f * s + 512.0f;          // biased: always > dot
  } else {
    int row = (bid - N_PATCH / 4) * 4 + w;             // 0..1343
    const float* src = (row < 64) ? me + (size_t)row * C
                     : (row < 320) ? ge + (size_t)(row - 64) * C
                                   : se + (size_t)(row - 320) * C;
    float4 v = reinterpret_cast<const float4*>(src)[l];
    ushort4 h;
    h.x = f2bf(v.x); h.y = f2bf(v.y); h.z = f2bf(v.z); h.w = f2bf(v.w);
    *reinterpret_cast<ushort4*>(lblB + (size_t)row * C + l * 4) = h;
  }
}

// ---------------- MFMA scoring: 32 labels x patch chunk, packed-key top-3/lane ----------------
__global__ __launch_bounds__(256, 2) void k_score_mfma(
    const char* __restrict__ patchB, const char* __restrict__ lblB,
    const float* __restrict__ hp2,
    float* __restrict__ candS, int* __restrict__ candI) {
  __shared__ char patchS[2][32768];                    // double-buffered 64x512B tiles

  const int j = blockIdx.x;
  const int chunk = (j & 7) * 3 + (j >> 3) / NGRP;     // XCD-local chunks
  const int grp = (j >> 3) % NGRP;
  const int row0 = grp * LBLK;
  const int p_begin = chunk * CHUNKP;
  const int p_end = min(p_begin + CHUNKP, N_PATCH);
  const int tid = threadIdx.x;
  const int l = tid & 63, w = tid >> 6;

  // stage labels into patchS[1] (reclaimed as buf1 after frags read), swizzled
  char* lblS = patchS[1];
  #pragma unroll
  for (int it = 0; it < 4; ++it) {
    int u = it * 256 + tid;
    int r = u >> 5; int b = (u & 31) << 4;
    u32x4 v = *reinterpret_cast<const u32x4*>(lblB + (((size_t)(row0 + r)) << 9) + b);
    *reinterpret_cast<u32x4*>(lblS + (r << 9) + (b ^ ((r & 7) << 4))) = v;
  }
  __syncthreads();

  const int kq = (l >> 4) << 4;
  bf16x8 bf[2][8];
  #pragma unroll
  for (int nt = 0; nt < 2; ++nt) {
    int r = nt * 16 + (l & 15);
    int xm = (r & 7) << 4;
    #pragma unroll
    for (int ks = 0; ks < 8; ++ks)
      bf[nt][ks] = *reinterpret_cast<const bf16x8*>(lblS + (r << 9) + ((ks * 64 + kq) ^ xm));
  }

  unsigned int a0k = KINIT, a1k = KINIT, a2k = KINIT;
  unsigned int b0k = KINIT, b1k = KINIT, b2k = KINIT;

  const int ntiles = (p_end - p_begin + PTILE - 1) / PTILE;
  const int prA = (w << 4) + (l & 15);
  const int xmA = (prA & 7) << 4;
  const int psub = (w << 4) + ((l >> 4) << 2);
  const size_t glim = (size_t)N_PATCH * 512 - 16;

  int srcoff[8];
  #pragma unroll
  for (int i = 0; i < 8; ++i) {
    int u = (w << 13) + (i << 10) + (l << 4);
    srcoff[i] = (u & ~511) | ((u & 511) ^ (((u >> 9) & 7) << 4));
  }

  auto stage = [&](int tile0, int buf) {
    size_t tb = (size_t)tile0 << 9;
    char* dstb = patchS[buf] + (w << 13);
    if (tile0 + PTILE <= N_PATCH) {
      #pragma unroll
      for (int i = 0; i < 8; ++i)
        GLL(patchB + tb + srcoff[i], dstb + (i << 10));
    } else {
      #pragma unroll
      for (int i = 0; i < 8; ++i) {
        size_t a = tb + (size_t)srcoff[i];
        if (a > glim) a = glim;
        GLL(patchB + a, dstb + (i << 10));
      }
    }
  };

  stage(p_begin, 0);
  float4 hcur = *reinterpret_cast<const float4*>(hp2 + min(p_begin + psub, N_PATCH - 4));
  unsigned int lidx = (unsigned int)psub;              // local idx base; psub % 4 == 0

  for (int t = 0; t < ntiles; ++t) {
    const int tile0 = p_begin + t * PTILE;
    __syncthreads();                                   // buf[t&1] ready; prev reads done
    float4 hnext = hcur;
    if (t + 1 < ntiles) {
      int nt0 = tile0 + PTILE;
      stage(nt0, (t + 1) & 1);                         // in flight across this compute
      hnext = *reinterpret_cast<const float4*>(hp2 + min(nt0 + psub, N_PATCH - 4));
    }

    const char* ab = patchS[t & 1] + (prA << 9);
    bf16x8 a[8];
    #pragma unroll
    for (int ks = 0; ks < 8; ++ks)
      a[ks] = *reinterpret_cast<const bf16x8*>(ab + ((ks * 64 + kq) ^ xmA));
    f32x4 acc0 = {0.f, 0.f, 0.f, 0.f}, acc1 = {0.f, 0.f, 0.f, 0.f};
    __builtin_amdgcn_s_setprio(1);
    #pragma unroll
    for (int ks = 0; ks < 8; ++ks) {
      acc0 = __builtin_amdgcn_mfma_f32_16x16x32_bf16(a[ks], bf[0][ks], acc0, 0, 0, 0);
      acc1 = __builtin_amdgcn_mfma_f32_16x16x32_bf16(a[ks], bf[1][ks], acc1, 0, 0, 0);
    }
    __builtin_amdgcn_s_setprio(0);

    unsigned int l1 = lidx | 1u, l2 = lidx | 2u, l3 = lidx | 3u;
    if (tile0 + PTILE <= p_end) {                      // interior fast path
      KNET3(a0k, a1k, a2k, (__float_as_uint(hcur.x - acc0[0]) & SMASK) | lidx);
      KNET3(a0k, a1k, a2k, (__float_as_uint(hcur.y - acc0[1]) & SMASK) | l1);
      KNET3(a0k, a1k, a2k, (__float_as_uint(hcur.z - acc0[2]) & SMASK) | l2);
      KNET3(a0k, a1k, a2k, (__float_as_uint(hcur.w - acc0[3]) & SMASK) | l3);
      KNET3(b0k, b1k, b2k, (__float_as_uint(hcur.x - acc1[0]) & SMASK) | lidx);
      KNET3(b0k, b1k, b2k, (__float_as_uint(hcur.y - acc1[1]) & SMASK) | l1);
      KNET3(b0k, b1k, b2k, (__float_as_uint(hcur.z - acc1[2]) & SMASK) | l2);
      KNET3(b0k, b1k, b2k, (__float_as_uint(hcur.w - acc1[3]) & SMASK) | l3);
    } else {                                           // only last tile of chunk 23
      const int pg0 = tile0 + psub;
      unsigned int k0 = (pg0     < p_end) ? ((__float_as_uint(hcur.x - acc0[0]) & SMASK) | lidx) : KINIT;
      unsigned int k1 = (pg0 + 1 < p_end) ? ((__float_as_uint(hcur.y - acc0[1]) & SMASK) | l1) : KINIT;
      unsigned int k2 = (pg0 + 2 < p_end) ? ((__float_as_uint(hcur.z - acc0[2]) & SMASK) | l2) : KINIT;
      unsigned int k3 = (pg0 + 3 < p_end) ? ((__float_as_uint(hcur.w - acc0[3]) & SMASK) | l3) : KINIT;
      unsigned int m0 = (pg0     < p_end) ? ((__float_as_uint(hcur.x - acc1[0]) & SMASK) | lidx) : KINIT;
      unsigned int m1 = (pg0 + 1 < p_end) ? ((__float_as_uint(hcur.y - acc1[1]) & SMASK) | l1) : KINIT;
      unsigned int m2 = (pg0 + 2 < p_end) ? ((__float_as_uint(hcur.z - acc1[2]) & SMASK) | l2) : KINIT;
      unsigned int m3 = (pg0 + 3 < p_end) ? ((__float_as_uint(hcur.w - acc1[3]) & SMASK) | l3) : KINIT;
      KNET3(a0k, a1k, a2k, k0); KNET3(a0k, a1k, a2k, k1);
      KNET3(a0k, a1k, a2k, k2); KNET3(a0k, a1k, a2k, k3);
      KNET3(b0k, b1k, b2k, m0); KNET3(b0k, b1k, b2k, m1);
      KNET3(b0k, b1k, b2k, m2); KNET3(b0k, b1k, b2k, m3);
    }
    lidx += 64u;
    hcur = hnext;
  }
  __syncthreads();

  // merge 16 lane-subsets x 3 keys per label -> per (row, chunk) top-10
  unsigned int* ks_ = reinterpret_cast<unsigned int*>(patchS[0]);  // [32][16][3] u32
  const int sub = (w << 2) + (l >> 4);
  const int L = l & 15;
  {
    int base0 = (L * 16 + sub) * 3;
    int base1 = ((L + 16) * 16 + sub) * 3;
    ks_[base0 + 0] = a0k; ks_[base0 + 1] = a1k; ks_[base0 + 2] = a2k;
    ks_[base1 + 0] = b0k; ks_[base1 + 1] = b1k; ks_[base1 + 2] = b2k;
  }
  __syncthreads();
  if (tid < LBLK) {
    unsigned int fk[KCC];
    #pragma unroll
    for (int jj = 0; jj < KCC; ++jj) fk[jj] = KINIT;
    for (int q = 0; q < 48; ++q) {
      unsigned int v = ks_[tid * 48 + q];
      if (v < fk[KCC-1]) {
        fk[KCC-1] = v;
        #pragma unroll
        for (int qq = KCC-1; qq >= 1; --qq) {
          if (fk[qq] < fk[qq-1]) {
            unsigned int tv = fk[qq]; fk[qq] = fk[qq-1]; fk[qq-1] = tv;
          }
        }
      }
    }
    size_t o = ((size_t)(row0 + tid) * NCHUNK + chunk) * KCC;
    #pragma unroll
    for (int jj = 0; jj < KCC; ++jj) {
      candS[o + jj] = __uint_as_float(fk[jj] & SMASK);
      candI[o + jj] = p_begin + (int)(fk[jj] & 0x1FFFu);
    }
  }
}

// ---------------- fused: prefilter + exact fp32 rescore + top-9 + ctx_patch ----------------
__global__ __launch_bounds__(256) void k_rescore_ctx(
    const float* __restrict__ patchF,
    const float* __restrict__ me, const float* __restrict__ ge,
    const float* __restrict__ se,
    const float* __restrict__ hp2, const float* __restrict__ candS,
    const int* __restrict__ candI,
    float* __restrict__ ctx_m, float* __restrict__ ctx_gp, float* __restrict__ ctx_sp) {
  __shared__ float lrow[C];
  __shared__ float ss[NCAND];
  __shared__ int si[NCAND];
  __shared__ int selIdx[NSEL];
  __shared__ float s2[NSEL];
  __shared__ int top[KP];
  int row = blockIdx.x, t = threadIdx.x;
  const float* lsrc = (row < 64) ? me + (size_t)row * C
                    : (row < 320) ? ge + (size_t)(row - 64) * C
                                  : se + (size_t)(row - 320) * C;
  lrow[t] = lsrc[t];
  if (t < NCAND) {
    ss[t] = candS[(size_t)row * NCAND + t];
    si[t] = candI[(size_t)row * NCAND + t];
  }
  __syncthreads();
  if (t < NCAND) {                                     // all-pairs rank; keep approx-top-24
    float s = ss[t]; int id = si[t];
    int rank = 0;
    for (int q = 0; q < NCAND; ++q) {
      float v = ss[q];
      rank += (v < s) || (v == s && si[q] < id);
    }
    if (rank < NSEL) selIdx[rank] = id;
  }
  __syncthreads();
  {                                                    // exact rescore: 8 threads/candidate
    int c = t >> 3, l8 = t & 7;
    if (c < NSEL) {
      const float4* pr = reinterpret_cast<const float4*>(patchF + (size_t)selIdx[c] * C);
      const float4* lr = reinterpret_cast<const float4*>(lrow);
      float dx = 0.f, dy = 0.f, dz = 0.f, dw = 0.f;
      #pragma unroll
      for (int i = 0; i < 8; ++i) {
        float4 a = pr[l8 + 8*i], b = lr[l8 + 8*i];
        dx = fmaf(a.x, b.x, dx); dy = fmaf(a.y, b.y, dy);
        dz = fmaf(a.z, b.z, dz); dw = fmaf(a.w, b.w, dw);
      }
      float d = (dx + dy) + (dz + dw);
      #pragma unroll
      for (int off = 1; off < 8; off <<= 1) d += __shfl_xor(d, off, 64);
      if (l8 == 0) s2[c] = hp2[selIdx[c]] - d;         // biased, consistent ranking
    }
  }
  __syncthreads();
  if (t == 0) {
    float fs[KP]; int fi[KP];
    #pragma unroll
    for (int jj = 0; jj < KP; ++jj) { fs[jj] = FLT_MAX; fi[jj] = 0; }
    for (int q = 0; q < NSEL; ++q) {
      float v = s2[q];
      if (v < fs[KP-1]) {
        fs[KP-1] = v; fi[KP-1] = selIdx[q];
        #pragma unroll
        for (int qq = KP-1; qq >= 1; --qq) {
          if (fs[qq] < fs[qq-1]) {
            float ts = fs[qq]; fs[qq] = fs[qq-1]; fs[qq-1] = ts;
            int ti = fi[qq]; fi[qq] = fi[qq-1]; fi[qq-1] = ti;
          }
        }
      }
    }
    #pragma unroll
    for (int jj = 0; jj < KP; ++jj) top[jj] = fi[jj];
  }
  __syncthreads();
  float m = -FLT_MAX;
  #pragma unroll
  for (int jj = 0; jj < KP; ++jj)
    m = fmaxf(m, patchF[(size_t)top[jj] * C + t]);     // rows L1/L2-hot from rescore
  float* dst; int rr;
  if (row < 64)       { dst = ctx_m;  rr = row; }
  else if (row < 320) { dst = ctx_gp; rr = row - 64; }
  else                { dst = ctx_sp; rr = row - 320; }
  dst[(size_t)rr * C + t] = m - lrow[t];
}

// ---------------- device helper: dists of 4 q-rows (in qs) to nref rows of ref ----------------
static __device__ __forceinline__ void ctx_from_refs(
    const float (&qs)[4][C], float (&ds)[4][256], int (&sel)[4][4],
    const float* __restrict__ ref, int nref, int k,
    float* __restrict__ ctx, int row0, int t) {
  int w = t >> 6, ln = t & 63;
  int nk = nref >> 6;                                  // 1 or 4
  for (int kk = 0; kk < nk; ++kk) {                    // thread -> (q=w, ref=ln+64kk)
    int ri = ln + (kk << 6);
    const float4* rr = reinterpret_cast<const float4*>(ref + (size_t)ri * C);
    const float4* qq = reinterpret_cast<const float4*>(qs[w]);
    float dx = 0.f, dy = 0.f, dz = 0.f, dw = 0.f;
    #pragma unroll 8
    for (int i = 0; i < 64; ++i) {
      float4 a = rr[i], b = qq[i];
      float e;
      e = a.x - b.x; dx = fmaf(e, e, dx);
      e = a.y - b.y; dy = fmaf(e, e, dy);
      e = a.z - b.z; dz = fmaf(e, e, dz);
      e = a.w - b.w; dw = fmaf(e, e, dw);
    }
    ds[w][ri] = (dx + dy) + (dz + dw);
  }
  __syncthreads();
  {                                                    // wave w: top-k for q-row w
    for (int jj = 0; jj < k; ++jj) {
      float m = ds[w][ln]; int mi_ = ln;
      for (int o = 64; o < nref; o += 64) {
        float v = ds[w][ln + o];
        if (v < m) { m = v; mi_ = ln + o; }
      }
      #pragma unroll
      for (int off = 32; off; off >>= 1) {
        float om = __shfl_down(m, off, 64);
        int oi = __shfl_down(mi_, off, 64);
        if (om < m) { m = om; mi_ = oi; }
      }
      mi_ = __shfl(mi_, 0, 64);
      if (ln == 0) sel[w][jj] = mi_;
      ds[w][mi_] = FLT_MAX;
    }
  }
  __syncthreads();
  #pragma unroll 4
  for (int r = 0; r < 4; ++r) {
    float m = -FLT_MAX;
    for (int jj = 0; jj < k; ++jj) m = fmaxf(m, ref[(size_t)sel[r][jj] * C + t]);
    ctx[(size_t)(row0 + r) * C + t] = m - qs[r][t];
  }
}

// ---------------- ctx vs out_m for BOTH genre (k=4) and sub (k=3), one launch ----------------
__global__ __launch_bounds__(256) void k_ctx_mood(const float* __restrict__ genre_e,
                                                  const float* __restrict__ sub_e,
                                                  const float* __restrict__ out_m,
                                                  float* __restrict__ ctx_gm,
                                                  float* __restrict__ ctx_sm) {
  __shared__ __align__(16) float qs[4][C];
  __shared__ float ds[4][256];
  __shared__ int sel[4][4];
  int bid = blockIdx.x, t = threadIdx.x, w = t >> 6, ln = t & 63;
  const float* q; float* dst; int row0, k;
  if (bid < 64) { q = genre_e; dst = ctx_gm; row0 = bid * 4; k = 4; }
  else          { q = sub_e;   dst = ctx_sm; row0 = (bid - 64) * 4; k = 3; }
  *reinterpret_cast<float4*>(&qs[w][ln << 2]) =
      *reinterpret_cast<const float4*>(q + (size_t)(row0 + w) * C + (ln << 2));
  __syncthreads();
  ctx_from_refs(qs, ds, sel, out_m, 64, k, dst, row0, t);
}

// ---------------- ctx from one updated label set (4 q-rows/block) ----------------
__global__ __launch_bounds__(256) void k_ctx_lbl4(const float* __restrict__ q,
                                                  const float* __restrict__ ref,
                                                  int nref, int k, float* __restrict__ ctx) {
  __shared__ __align__(16) float qs[4][C];
  __shared__ float ds[4][256];
  __shared__ int sel[4][4];
  int row0 = blockIdx.x * 4, t = threadIdx.x, w = t >> 6, ln = t & 63;
  *reinterpret_cast<float4*>(&qs[w][ln << 2]) =
      *reinterpret_cast<const float4*>(q + (size_t)(row0 + w) * C + (ln << 2));
  __syncthreads();
  ctx_from_refs(qs, ds, sel, ref, nref, k, ctx, row0, t);
}

// ---------------- fused concat @ W + bias + residual + LayerNorm, R rows/block ----------------
template <int R>
__global__ __launch_bounds__(256) void k_out(
    const float* __restrict__ emb, const float* __restrict__ c0,
    const float* __restrict__ c1, const float* __restrict__ c2,
    const float* __restrict__ W, const float* __restrict__ bias,
    const float* __restrict__ gamma, const float* __restrict__ beta,
    float* __restrict__ out, int nin) {
  __shared__ float x[R][1024];
  __shared__ float red[4][R];
  const int row0 = blockIdx.x * R, t = threadIdx.x;
  const int nv = nin >> 2;
  #pragma unroll
  for (int rr = 0; rr < R; ++rr) {
    if (t < nv) {
      int seg = t >> 6;
      const float* src = seg == 0 ? emb : seg == 1 ? c0 : seg == 2 ? c1 : c2;
      *reinterpret_cast<float4*>(&x[rr][t << 2]) =
          *reinterpret_cast<const float4*>(src + (size_t)(row0 + rr) * C + ((t & 63) << 2));
    }
  }
  __syncthreads();
  float acc[R];
  #pragma unroll
  for (int rr = 0; rr < R; ++rr) acc[rr] = 0.f;
  for (int i0 = 0; i0 < nin; i0 += 8) {
    float wv[8];
    #pragma unroll
    for (int u = 0; u < 8; ++u) wv[u] = W[(size_t)(i0 + u) * C + t];  // independent loads
    #pragma unroll
    for (int u = 0; u < 8; ++u) {
      #pragma unroll
      for (int rr = 0; rr < R; ++rr) acc[rr] = fmaf(x[rr][i0 + u], wv[u], acc[rr]);
    }
  }
  float bv = bias[t];
  float y[R], d[R];
  int wv_ = t >> 6, ln = t & 63;
  #pragma unroll
  for (int rr = 0; rr < R; ++rr) {
    y[rr] = x[rr][t] + acc[rr] + bv;                   // x[rr][t] == emb value
    float sum = y[rr];
    #pragma unroll
    for (int off = 32; off; off >>= 1) sum += __shfl_down(sum, off, 64);
    if (ln == 0) red[wv_][rr] = sum;
  }
  __syncthreads();
  float mu[R];
  #pragma unroll
  for (int rr = 0; rr < R; ++rr)
    mu[rr] = (red[0][rr] + red[1][rr] + red[2][rr] + red[3][rr]) * (1.f / C);
  __syncthreads();
  #pragma unroll
  for (int rr = 0; rr < R; ++rr) {
    d[rr] = y[rr] - mu[rr];
    float sq = d[rr] * d[rr];
    #pragma unroll
    for (int off = 32; off; off >>= 1) sq += __shfl_down(sq, off, 64);
    if (ln == 0) red[wv_][rr] = sq;
  }
  __syncthreads();
  #pragma unroll
  for (int rr = 0; rr < R; ++rr) {
    float var = (red[0][rr] + red[1][rr] + red[2][rr] + red[3][rr]) * (1.f / C);
    out[(size_t)(row0 + rr) * C + t] = d[rr] * rsqrtf(var + 1e-5f) * gamma[t] + beta[t];
  }
}

extern "C" void kernel_launch(void* const* d_in, const int* in_sizes, int n_in,
                              void* d_out, int out_size, void* d_ws, size_t ws_size,
                              hipStream_t stream) {
  const float* patch   = (const float*)d_in[0];
  const float* mood_e  = (const float*)d_in[1];
  const float* genre_e = (const float*)d_in[2];
  const float* sub_e   = (const float*)d_in[3];
  const float* Wm  = (const float*)d_in[4];
  const float* bm  = (const float*)d_in[5];
  const float* Wg  = (const float*)d_in[6];
  const float* bg  = (const float*)d_in[7];
  const float* Ws  = (const float*)d_in[8];
  const float* bs_ = (const float*)d_in[9];
  const float* gm  = (const float*)d_in[10];
  const float* bnm = (const float*)d_in[11];
  const float* gg  = (const float*)d_in[12];
  const float* bng = (const float*)d_in[13];
  const float* gs  = (const float*)d_in[14];
  const float* bns = (const float*)d_in[15];

  char* ws = (char*)d_ws;
  size_t off = 0;
  auto alloc = [&](size_t bytes) { void* p = ws + off; off = (off + bytes + 255) & ~(size_t)255; return p; };
  unsigned short* patchB = (unsigned short*)alloc((size_t)N_PATCH * C * 2);   // 51.2 MB
  unsigned short* lblB   = (unsigned short*)alloc((size_t)S_TOT * C * 2);
  float* hp2   = (float*)alloc((size_t)N_PATCH * 4);
  float* candS = (float*)alloc((size_t)S_TOT * NCAND * 4);
  int*   candI = (int*)  alloc((size_t)S_TOT * NCAND * 4);
  float* ctx_m  = (float*)alloc((size_t)64   * C * 4);
  float* ctx_gp = (float*)alloc((size_t)256  * C * 4);
  float* ctx_gm = (float*)alloc((size_t)256  * C * 4);
  float* ctx_sp = (float*)alloc((size_t)1024 * C * 4);
  float* ctx_sm = (float*)alloc((size_t)1024 * C * 4);
  float* ctx_sg = (float*)alloc((size_t)1024 * C * 4);

  float* out_m = (float*)d_out;
  float* out_g = out_m + 64 * C;
  float* out_s = out_g + 256 * C;

  k_prep<<<N_PATCH / 4 + S_TOT / 4, 256, 0, stream>>>(patch, mood_e, genre_e, sub_e,
                                                      patchB, lblB, hp2);
  k_score_mfma<<<NGRP * NCHUNK, 256, 0, stream>>>((const char*)patchB, (const char*)lblB,
                                                  hp2, candS, candI);
  k_rescore_ctx<<<S_TOT, 256, 0, stream>>>(patch, mood_e, genre_e, sub_e, hp2,
                                           candS, candI, ctx_m, ctx_gp, ctx_sp);
  k_out<2><<<32, 256, 0, stream>>>(mood_e, ctx_m, nullptr, nullptr, Wm, bm, gm, bnm,
                                   out_m, 512);
  k_ctx_mood<<<320, 256, 0, stream>>>(genre_e, sub_e, out_m, ctx_gm, ctx_sm);
  k_out<2><<<128, 256, 0, stream>>>(genre_e, ctx_gp, ctx_gm, nullptr, Wg, bg, gg, bng,
                                    out_g, 768);
  k_ctx_lbl4<<<256, 256, 0, stream>>>(sub_e, out_g, 256, 4, ctx_sg);
  k_out<4><<<256, 256, 0, stream>>>(sub_e, ctx_sp, ctx_sm, ctx_sg, Ws, bs_, gs, bns,
                                    out_s, 1024);
}

// Round 7
// 283.012 us; speedup vs baseline: 7.1220x; 1.0283x over previous
//
#include <hip/hip_runtime.h>
#include <float.h>

#define N_PATCH 100000
#define C 256
#define S_TOT 1344
#define LBLK 32
#define NGRP 42
#define NCHUNK 24
#define CHUNKP 4224          // 66 steps of 64; tile-aligned; 24*4224 >= 100000
#define KCC 10               // per-(row,chunk) kept candidates
#define NCAND (NCHUNK*KCC)   // 240
#define NSEL 24              // exact-rescored candidates
#define KP 9
#define SMASK 0xFFFFE000u    // keep sign+exp+10 mantissa bits; low 13 bits = local idx
#define KINIT 0x7F7FFFFFu    // FLT_MAX pattern

typedef __attribute__((ext_vector_type(8))) short bf16x8;
typedef __attribute__((ext_vector_type(4))) float f32x4;
typedef __attribute__((ext_vector_type(4))) unsigned int u32x4;

#define GLL(gp, lp) __builtin_amdgcn_global_load_lds(                        \
    (__attribute__((address_space(1))) void*)(gp),                           \
    (__attribute__((address_space(3))) void*)(lp), 16, 0, 0)

static __device__ __forceinline__ unsigned short f2bf(float f) {
  unsigned int u = __float_as_uint(f);
  return (unsigned short)((u + 0x7FFFu + ((u >> 16) & 1u)) >> 16);
}

// u32 sorted-3 min/max network insert (score-packed keys)
#define KNET3(K0, K1, K2, KV)                               \
  { unsigned int _kv = (KV);                                \
    K2 = min(K2, max(K1, _kv));                             \
    K1 = min(K1, max(K0, _kv));                             \
    K0 = min(K0, _kv); }

// ---------------- fused prep: patches (bf16 + biased half-norm) and labels ----------------
__global__ __launch_bounds__(256) void k_prep(
    const float* __restrict__ patch, const float* __restrict__ me,
    const float* __restrict__ ge, const float* __restrict__ se,
    unsigned short* __restrict__ patchB, unsigned short* __restrict__ lblB,
    float* __restrict__ hp2) {
  int bid = blockIdx.x;
  int w = threadIdx.x >> 6, l = threadIdx.x & 63;
  if (bid < N_PATCH / 4) {
    int row = bid * 4 + w;
    float4 p = reinterpret_cast<const float4*>(patch + (size_t)row * C)[l];
    ushort4 h;
    h.x = f2bf(p.x); h.y = f2bf(p.y); h.z = f2bf(p.z); h.w = f2bf(p.w);
    *reinterpret_cast<ushort4*>(patchB + (size_t)row * C + l * 4) = h;
    float s = p.x*p.x + p.y*p.y + p.z*p.z + p.w*p.w;
    #pragma unroll
    for (int off = 32; off; off >>= 1) s += __shfl_down(s, off, 64);
    if (l == 0) hp2[row] = 0.5f * s + 512.0f;          // biased: always > dot
  } else {
    int row = (bid - N_PATCH / 4) * 4 + w;             // 0..1343
    const float* src = (row < 64) ? me + (size_t)row * C
                     : (row < 320) ? ge + (size_t)(row - 64) * C
                                   : se + (size_t)(row - 320) * C;
    float4 v = reinterpret_cast<const float4*>(src)[l];
    ushort4 h;
    h.x = f2bf(v.x); h.y = f2bf(v.y); h.z = f2bf(v.z); h.w = f2bf(v.w);
    *reinterpret_cast<ushort4*>(lblB + (size_t)row * C + l * 4) = h;
  }
}

// ---------------- MFMA scoring: barrier-free wave-private tiles, counted vmcnt ----------------
// Each wave owns a private double-buffered 8KB (16-patch) LDS tile. Per step it
// issues exactly 9 VMEM ops (1 hp2 dwordx4 + 8 global_load_lds); s_waitcnt vmcnt(9)
// guarantees the previous step's group landed while the next stays in flight.
__global__ __launch_bounds__(256, 2) void k_score_mfma(
    const char* __restrict__ patchB, const char* __restrict__ lblB,
    const float* __restrict__ hp2,
    float* __restrict__ candS, int* __restrict__ candI) {
  __shared__ char patchS[65536];                       // [wave][2buf][8192]

  const int j = blockIdx.x;
  const int chunk = (j & 7) * 3 + (j >> 3) / NGRP;     // XCD-local chunks
  const int grp = (j >> 3) % NGRP;
  const int row0 = grp * LBLK;
  const int p_begin = chunk * CHUNKP;
  const int p_end = min(p_begin + CHUNKP, N_PATCH);
  const int tid = threadIdx.x;
  const int l = tid & 63, w = tid >> 6;

  // stage labels into first 16KB, swizzled
  char* lblS = patchS;
  #pragma unroll
  for (int it = 0; it < 4; ++it) {
    int u = it * 256 + tid;
    int r = u >> 5; int b = (u & 31) << 4;
    u32x4 v = *reinterpret_cast<const u32x4*>(lblB + (((size_t)(row0 + r)) << 9) + b);
    *reinterpret_cast<u32x4*>(lblS + (r << 9) + (b ^ ((r & 7) << 4))) = v;
  }
  __syncthreads();

  const int kq = (l >> 4) << 4;
  bf16x8 bf[2][8];
  #pragma unroll
  for (int nt = 0; nt < 2; ++nt) {
    int r = nt * 16 + (l & 15);
    int xm = (r & 7) << 4;
    #pragma unroll
    for (int ks = 0; ks < 8; ++ks)
      bf[nt][ks] = *reinterpret_cast<const bf16x8*>(lblS + (r << 9) + ((ks * 64 + kq) ^ xm));
  }
  __syncthreads();                                     // frags read; LDS now wave-private

  unsigned int a0k = KINIT, a1k = KINIT, a2k = KINIT;
  unsigned int b0k = KINIT, b1k = KINIT, b2k = KINIT;

  const int nsteps = (p_end - p_begin + 63) >> 6;      // 66 (45 for chunk 23)
  char* wbase = patchS + (w << 14);                    // wave's 16KB
  const int prow = l & 15;
  const int xmA = (prow & 7) << 4;
  const int psub = (l >> 4) << 2;                      // 0,4,8,12 within wave-tile
  const size_t glim = (size_t)N_PATCH * 512 - 16;

  int srcoff[8];
  #pragma unroll
  for (int i = 0; i < 8; ++i) {
    int u = (i << 10) + (l << 4);
    srcoff[i] = (u & ~511) | ((u & 511) ^ (((u >> 9) & 7) << 4));
  }

  auto stage = [&](int t, int buf) {                   // 8 GLL, wave-private dest
    int tile0 = p_begin + t * 64 + w * 16;
    size_t tb = (size_t)tile0 << 9;
    char* dstb = wbase + (buf << 13);
    if (tile0 + 16 <= N_PATCH) {
      #pragma unroll
      for (int i = 0; i < 8; ++i)
        GLL(patchB + tb + srcoff[i], dstb + (i << 10));
    } else {
      #pragma unroll
      for (int i = 0; i < 8; ++i) {
        size_t a2 = tb + (size_t)srcoff[i];
        if (a2 > glim) a2 = glim;
        GLL(patchB + a2, dstb + (i << 10));
      }
    }
  };

  // prologue group 0: hp2 first, then 8 GLL (order pinned)
  float4 hcur = *reinterpret_cast<const float4*>(
      hp2 + min(p_begin + w * 16 + psub, N_PATCH - 4));
  __builtin_amdgcn_sched_barrier(0);
  stage(0, 0);
  unsigned int lidx = (unsigned int)(w * 16 + psub);

  for (int t = 0; t < nsteps; ++t) {
    float4 hnext = hcur;
    if (t + 1 < nsteps) {                              // group t+1: hp2 then 8 GLL
      int nt0 = p_begin + (t + 1) * 64 + w * 16;
      hnext = *reinterpret_cast<const float4*>(hp2 + min(nt0 + psub, N_PATCH - 4));
      __builtin_amdgcn_sched_barrier(0);
      stage(t + 1, (t + 1) & 1);
      asm volatile("s_waitcnt vmcnt(9)" ::: "memory"); // group t fully landed
    } else {
      asm volatile("s_waitcnt vmcnt(0)" ::: "memory");
    }
    __builtin_amdgcn_sched_barrier(0);

    const char* ab = wbase + ((t & 1) << 13) + (prow << 9);
    bf16x8 a[8];
    #pragma unroll
    for (int ks = 0; ks < 8; ++ks)
      a[ks] = *reinterpret_cast<const bf16x8*>(ab + ((ks * 64 + kq) ^ xmA));
    f32x4 acc0 = {0.f, 0.f, 0.f, 0.f}, acc1 = {0.f, 0.f, 0.f, 0.f};
    __builtin_amdgcn_s_setprio(1);
    #pragma unroll
    for (int ks = 0; ks < 8; ++ks) {
      acc0 = __builtin_amdgcn_mfma_f32_16x16x32_bf16(a[ks], bf[0][ks], acc0, 0, 0, 0);
      acc1 = __builtin_amdgcn_mfma_f32_16x16x32_bf16(a[ks], bf[1][ks], acc1, 0, 0, 0);
    }
    __builtin_amdgcn_s_setprio(0);

    const int tw0 = p_begin + t * 64 + w * 16;
    unsigned int l1 = lidx | 1u, l2 = lidx | 2u, l3 = lidx | 3u;
    if (tw0 + 16 <= p_end) {                           // interior fast path (wave-uniform)
      KNET3(a0k, a1k, a2k, (__float_as_uint(hcur.x - acc0[0]) & SMASK) | lidx);
      KNET3(a0k, a1k, a2k, (__float_as_uint(hcur.y - acc0[1]) & SMASK) | l1);
      KNET3(a0k, a1k, a2k, (__float_as_uint(hcur.z - acc0[2]) & SMASK) | l2);
      KNET3(a0k, a1k, a2k, (__float_as_uint(hcur.w - acc0[3]) & SMASK) | l3);
      KNET3(b0k, b1k, b2k, (__float_as_uint(hcur.x - acc1[0]) & SMASK) | lidx);
      KNET3(b0k, b1k, b2k, (__float_as_uint(hcur.y - acc1[1]) & SMASK) | l1);
      KNET3(b0k, b1k, b2k, (__float_as_uint(hcur.z - acc1[2]) & SMASK) | l2);
      KNET3(b0k, b1k, b2k, (__float_as_uint(hcur.w - acc1[3]) & SMASK) | l3);
    } else {                                           // tail tiles only
      const int pg0 = tw0 + psub;
      unsigned int k0 = (pg0     < p_end) ? ((__float_as_uint(hcur.x - acc0[0]) & SMASK) | lidx) : KINIT;
      unsigned int k1 = (pg0 + 1 < p_end) ? ((__float_as_uint(hcur.y - acc0[1]) & SMASK) | l1) : KINIT;
      unsigned int k2 = (pg0 + 2 < p_end) ? ((__float_as_uint(hcur.z - acc0[2]) & SMASK) | l2) : KINIT;
      unsigned int k3 = (pg0 + 3 < p_end) ? ((__float_as_uint(hcur.w - acc0[3]) & SMASK) | l3) : KINIT;
      unsigned int m0 = (pg0     < p_end) ? ((__float_as_uint(hcur.x - acc1[0]) & SMASK) | lidx) : KINIT;
      unsigned int m1 = (pg0 + 1 < p_end) ? ((__float_as_uint(hcur.y - acc1[1]) & SMASK) | l1) : KINIT;
      unsigned int m2 = (pg0 + 2 < p_end) ? ((__float_as_uint(hcur.z - acc1[2]) & SMASK) | l2) : KINIT;
      unsigned int m3 = (pg0 + 3 < p_end) ? ((__float_as_uint(hcur.w - acc1[3]) & SMASK) | l3) : KINIT;
      KNET3(a0k, a1k, a2k, k0); KNET3(a0k, a1k, a2k, k1);
      KNET3(a0k, a1k, a2k, k2); KNET3(a0k, a1k, a2k, k3);
      KNET3(b0k, b1k, b2k, m0); KNET3(b0k, b1k, b2k, m1);
      KNET3(b0k, b1k, b2k, m2); KNET3(b0k, b1k, b2k, m3);
    }
    lidx += 64u;
    hcur = hnext;
  }
  __syncthreads();                                     // all waves done with LDS

  // merge 16 lane-subsets x 3 keys per label -> per (row, chunk) top-10
  unsigned int* ks_ = reinterpret_cast<unsigned int*>(patchS);     // [32][16][3] u32
  const int sub = (w << 2) + (l >> 4);
  const int L = l & 15;
  {
    int base0 = (L * 16 + sub) * 3;
    int base1 = ((L + 16) * 16 + sub) * 3;
    ks_[base0 + 0] = a0k; ks_[base0 + 1] = a1k; ks_[base0 + 2] = a2k;
    ks_[base1 + 0] = b0k; ks_[base1 + 1] = b1k; ks_[base1 + 2] = b2k;
  }
  __syncthreads();
  if (tid < LBLK) {
    unsigned int fk[KCC];
    #pragma unroll
    for (int jj = 0; jj < KCC; ++jj) fk[jj] = KINIT;
    for (int q = 0; q < 48; ++q) {
      unsigned int v = ks_[tid * 48 + q];
      if (v < fk[KCC-1]) {
        fk[KCC-1] = v;
        #pragma unroll
        for (int qq = KCC-1; qq >= 1; --qq) {
          if (fk[qq] < fk[qq-1]) {
            unsigned int tv = fk[qq]; fk[qq] = fk[qq-1]; fk[qq-1] = tv;
          }
        }
      }
    }
    size_t o = ((size_t)(row0 + tid) * NCHUNK + chunk) * KCC;
    #pragma unroll
    for (int jj = 0; jj < KCC; ++jj) {
      candS[o + jj] = __uint_as_float(fk[jj] & SMASK);
      candI[o + jj] = p_begin + (int)(fk[jj] & 0x1FFFu);
    }
  }
}

// ---------------- fused: prefilter + exact fp32 rescore + top-9 + ctx_patch ----------------
__global__ __launch_bounds__(256) void k_rescore_ctx(
    const float* __restrict__ patchF,
    const float* __restrict__ me, const float* __restrict__ ge,
    const float* __restrict__ se,
    const float* __restrict__ hp2, const float* __restrict__ candS,
    const int* __restrict__ candI,
    float* __restrict__ ctx_m, float* __restrict__ ctx_gp, float* __restrict__ ctx_sp) {
  __shared__ float lrow[C];
  __shared__ float ss[NCAND];
  __shared__ int si[NCAND];
  __shared__ int selIdx[NSEL];
  __shared__ float s2[NSEL];
  __shared__ int top[KP];
  int row = blockIdx.x, t = threadIdx.x;
  const float* lsrc = (row < 64) ? me + (size_t)row * C
                    : (row < 320) ? ge + (size_t)(row - 64) * C
                                  : se + (size_t)(row - 320) * C;
  lrow[t] = lsrc[t];
  if (t < NCAND) {
    ss[t] = candS[(size_t)row * NCAND + t];
    si[t] = candI[(size_t)row * NCAND + t];
  }
  __syncthreads();
  if (t < NCAND) {
    float s = ss[t]; int id = si[t];
    int rank = 0;
    for (int q = 0; q < NCAND; ++q) {
      float v = ss[q];
      rank += (v < s) || (v == s && si[q] < id);
    }
    if (rank < NSEL) selIdx[rank] = id;
  }
  __syncthreads();
  {
    int c = t >> 3, l8 = t & 7;
    if (c < NSEL) {
      const float4* pr = reinterpret_cast<const float4*>(patchF + (size_t)selIdx[c] * C);
      const float4* lr = reinterpret_cast<const float4*>(lrow);
      float dx = 0.f, dy = 0.f, dz = 0.f, dw = 0.f;
      #pragma unroll
      for (int i = 0; i < 8; ++i) {
        float4 a = pr[l8 + 8*i], b = lr[l8 + 8*i];
        dx = fmaf(a.x, b.x, dx); dy = fmaf(a.y, b.y, dy);
        dz = fmaf(a.z, b.z, dz); dw = fmaf(a.w, b.w, dw);
      }
      float d = (dx + dy) + (dz + dw);
      #pragma unroll
      for (int off = 1; off < 8; off <<= 1) d += __shfl_xor(d, off, 64);
      if (l8 == 0) s2[c] = hp2[selIdx[c]] - d;
    }
  }
  __syncthreads();
  if (t == 0) {
    float fs[KP]; int fi[KP];
    #pragma unroll
    for (int jj = 0; jj < KP; ++jj) { fs[jj] = FLT_MAX; fi[jj] = 0; }
    for (int q = 0; q < NSEL; ++q) {
      float v = s2[q];
      if (v < fs[KP-1]) {
        fs[KP-1] = v; fi[KP-1] = selIdx[q];
        #pragma unroll
        for (int qq = KP-1; qq >= 1; --qq) {
          if (fs[qq] < fs[qq-1]) {
            float ts = fs[qq]; fs[qq] = fs[qq-1]; fs[qq-1] = ts;
            int ti = fi[qq]; fi[qq] = fi[qq-1]; fi[qq-1] = ti;
          }
        }
      }
    }
    #pragma unroll
    for (int jj = 0; jj < KP; ++jj) top[jj] = fi[jj];
  }
  __syncthreads();
  float m = -FLT_MAX;
  #pragma unroll
  for (int jj = 0; jj < KP; ++jj)
    m = fmaxf(m, patchF[(size_t)top[jj] * C + t]);
  float* dst; int rr;
  if (row < 64)       { dst = ctx_m;  rr = row; }
  else if (row < 320) { dst = ctx_gp; rr = row - 64; }
  else                { dst = ctx_sp; rr = row - 320; }
  dst[(size_t)rr * C + t] = m - lrow[t];
}

// ---------------- mood output: concat @ W + bias + residual + LN, 2 rows/block ----------------
template <int R>
__global__ __launch_bounds__(256) void k_out(
    const float* __restrict__ emb, const float* __restrict__ c0,
    const float* __restrict__ c1, const float* __restrict__ c2,
    const float* __restrict__ W, const float* __restrict__ bias,
    const float* __restrict__ gamma, const float* __restrict__ beta,
    float* __restrict__ out, int nin) {
  __shared__ float x[R][1024];
  __shared__ float red[4][R];
  const int row0 = blockIdx.x * R, t = threadIdx.x;
  const int nv = nin >> 2;
  #pragma unroll
  for (int rr = 0; rr < R; ++rr) {
    if (t < nv) {
      int seg = t >> 6;
      const float* src = seg == 0 ? emb : seg == 1 ? c0 : seg == 2 ? c1 : c2;
      *reinterpret_cast<float4*>(&x[rr][t << 2]) =
          *reinterpret_cast<const float4*>(src + (size_t)(row0 + rr) * C + ((t & 63) << 2));
    }
  }
  __syncthreads();
  float acc[R];
  #pragma unroll
  for (int rr = 0; rr < R; ++rr) acc[rr] = 0.f;
  for (int i0 = 0; i0 < nin; i0 += 8) {
    float wv[8];
    #pragma unroll
    for (int u = 0; u < 8; ++u) wv[u] = W[(size_t)(i0 + u) * C + t];
    #pragma unroll
    for (int u = 0; u < 8; ++u) {
      #pragma unroll
      for (int rr = 0; rr < R; ++rr) acc[rr] = fmaf(x[rr][i0 + u], wv[u], acc[rr]);
    }
  }
  float bv = bias[t];
  float y[R], d[R];
  int wv_ = t >> 6, ln = t & 63;
  #pragma unroll
  for (int rr = 0; rr < R; ++rr) {
    y[rr] = x[rr][t] + acc[rr] + bv;
    float sum = y[rr];
    #pragma unroll
    for (int off = 32; off; off >>= 1) sum += __shfl_down(sum, off, 64);
    if (ln == 0) red[wv_][rr] = sum;
  }
  __syncthreads();
  float mu[R];
  #pragma unroll
  for (int rr = 0; rr < R; ++rr)
    mu[rr] = (red[0][rr] + red[1][rr] + red[2][rr] + red[3][rr]) * (1.f / C);
  __syncthreads();
  #pragma unroll
  for (int rr = 0; rr < R; ++rr) {
    d[rr] = y[rr] - mu[rr];
    float sq = d[rr] * d[rr];
    #pragma unroll
    for (int off = 32; off; off >>= 1) sq += __shfl_down(sq, off, 64);
    if (ln == 0) red[wv_][rr] = sq;
  }
  __syncthreads();
  #pragma unroll
  for (int rr = 0; rr < R; ++rr) {
    float var = (red[0][rr] + red[1][rr] + red[2][rr] + red[3][rr]) * (1.f / C);
    out[(size_t)(row0 + rr) * C + t] = d[rr] * rsqrtf(var + 1e-5f) * gamma[t] + beta[t];
  }
}

// ---------------- genre: fused ctx_gm (vs out_m) + concat GEMM + LN, 2 rows/block ----------------
__global__ __launch_bounds__(256) void k_out_g(
    const float* __restrict__ genre_e, const float* __restrict__ ctx_gp,
    const float* __restrict__ out_m,
    const float* __restrict__ W, const float* __restrict__ bias,
    const float* __restrict__ gamma, const float* __restrict__ beta,
    float* __restrict__ out) {
  __shared__ float x[2][1024];
  __shared__ float ds[2][64];
  __shared__ int sel[2][4];
  __shared__ float red[4][2];
  const int row0 = blockIdx.x * 2, t = threadIdx.x;
  const int w = t >> 6, ln = t & 63;
  {                                                    // load emb + ctx_gp segments
    int rr = t >> 7, seg = (t >> 6) & 1, c4 = (t & 63) << 2;
    const float* src = seg ? ctx_gp : genre_e;
    *reinterpret_cast<float4*>(&x[rr][seg * 256 + c4]) =
        *reinterpret_cast<const float4*>(src + (size_t)(row0 + rr) * C + c4);
  }
  __syncthreads();
  if (t < 128) {                                       // dist: 2 q x 64 refs
    int rr = t >> 6, ri = t & 63;
    const float4* rp = reinterpret_cast<const float4*>(out_m + (size_t)ri * C);
    float dx = 0.f, dy = 0.f, dz = 0.f, dw = 0.f;
    #pragma unroll 8
    for (int i = 0; i < 64; ++i) {
      float4 a = rp[i];
      float4 q4 = *reinterpret_cast<const float4*>(&x[rr][i << 2]);
      float e;
      e = a.x - q4.x; dx = fmaf(e, e, dx);
      e = a.y - q4.y; dy = fmaf(e, e, dy);
      e = a.z - q4.z; dz = fmaf(e, e, dz);
      e = a.w - q4.w; dw = fmaf(e, e, dw);
    }
    ds[rr][ri] = (dx + dy) + (dz + dw);
  }
  __syncthreads();
  if (w < 2) {                                         // top-4 per q-row
    for (int jj = 0; jj < 4; ++jj) {
      float m = ds[w][ln]; int mi_ = ln;
      #pragma unroll
      for (int off = 32; off; off >>= 1) {
        float om = __shfl_down(m, off, 64);
        int oi = __shfl_down(mi_, off, 64);
        if (om < m) { m = om; mi_ = oi; }
      }
      mi_ = __shfl(mi_, 0, 64);
      if (ln == 0) sel[w][jj] = mi_;
      ds[w][mi_] = FLT_MAX;
    }
  }
  __syncthreads();
  #pragma unroll
  for (int rr = 0; rr < 2; ++rr) {                     // ctx_gm into x[rr][512..768]
    float m = -FLT_MAX;
    #pragma unroll
    for (int jj = 0; jj < 4; ++jj) m = fmaxf(m, out_m[(size_t)sel[rr][jj] * C + t]);
    x[rr][512 + t] = m - x[rr][t];
  }
  __syncthreads();
  float acc0 = 0.f, acc1 = 0.f;                        // GEMM nin=768
  for (int i0 = 0; i0 < 768; i0 += 8) {
    float wv[8];
    #pragma unroll
    for (int u = 0; u < 8; ++u) wv[u] = W[(size_t)(i0 + u) * C + t];
    #pragma unroll
    for (int u = 0; u < 8; ++u) {
      acc0 = fmaf(x[0][i0 + u], wv[u], acc0);
      acc1 = fmaf(x[1][i0 + u], wv[u], acc1);
    }
  }
  float bv = bias[t];
  float y[2] = {x[0][t] + acc0 + bv, x[1][t] + acc1 + bv};
  float d[2];
  #pragma unroll
  for (int rr = 0; rr < 2; ++rr) {
    float sum = y[rr];
    #pragma unroll
    for (int off = 32; off; off >>= 1) sum += __shfl_down(sum, off, 64);
    if (ln == 0) red[w][rr] = sum;
  }
  __syncthreads();
  float mu[2];
  #pragma unroll
  for (int rr = 0; rr < 2; ++rr)
    mu[rr] = (red[0][rr] + red[1][rr] + red[2][rr] + red[3][rr]) * (1.f / C);
  __syncthreads();
  #pragma unroll
  for (int rr = 0; rr < 2; ++rr) {
    d[rr] = y[rr] - mu[rr];
    float sq = d[rr] * d[rr];
    #pragma unroll
    for (int off = 32; off; off >>= 1) sq += __shfl_down(sq, off, 64);
    if (ln == 0) red[w][rr] = sq;
  }
  __syncthreads();
  #pragma unroll
  for (int rr = 0; rr < 2; ++rr) {
    float var = (red[0][rr] + red[1][rr] + red[2][rr] + red[3][rr]) * (1.f / C);
    out[(size_t)(row0 + rr) * C + t] = d[rr] * rsqrtf(var + 1e-5f) * gamma[t] + beta[t];
  }
}

// ---------------- sub: fused ctx_sm (vs out_m,k=3) + ctx_sg (vs out_g,k=4) + GEMM + LN ----------------
__global__ __launch_bounds__(256) void k_out_s(
    const float* __restrict__ sub_e, const float* __restrict__ ctx_sp,
    const float* __restrict__ out_m, const float* __restrict__ out_g,
    const float* __restrict__ W, const float* __restrict__ bias,
    const float* __restrict__ gamma, const float* __restrict__ beta,
    float* __restrict__ out) {
  __shared__ float x[4][1024];
  __shared__ float ds[4][256];
  __shared__ int sel[4][4];
  __shared__ float red[4][4];
  const int row0 = blockIdx.x * 4, t = threadIdx.x;
  const int w = t >> 6, ln = t & 63;
  #pragma unroll
  for (int u = 0; u < 2; ++u) {                        // load emb + ctx_sp segments
    int idx = u * 256 + t;
    int rr = idx >> 7, seg = (idx >> 6) & 1, c4 = (idx & 63) << 2;
    const float* src = seg ? ctx_sp : sub_e;
    *reinterpret_cast<float4*>(&x[rr][seg * 256 + c4]) =
        *reinterpret_cast<const float4*>(src + (size_t)(row0 + rr) * C + c4);
  }
  __syncthreads();
  {                                                    // ctx_sm dist: 4 q x 64 refs
    int rr = t >> 6, ri = t & 63;
    const float4* rp = reinterpret_cast<const float4*>(out_m + (size_t)ri * C);
    float dx = 0.f, dy = 0.f, dz = 0.f, dw = 0.f;
    #pragma unroll 8
    for (int i = 0; i < 64; ++i) {
      float4 a = rp[i];
      float4 q4 = *reinterpret_cast<const float4*>(&x[rr][i << 2]);
      float e;
      e = a.x - q4.x; dx = fmaf(e, e, dx);
      e = a.y - q4.y; dy = fmaf(e, e, dy);
      e = a.z - q4.z; dz = fmaf(e, e, dz);
      e = a.w - q4.w; dw = fmaf(e, e, dw);
    }
    ds[rr][ri] = (dx + dy) + (dz + dw);
  }
  __syncthreads();
  for (int jj = 0; jj < 3; ++jj) {                     // top-3 per row (wave w = row w)
    float m = ds[w][ln]; int mi_ = ln;
    #pragma unroll
    for (int off = 32; off; off >>= 1) {
      float om = __shfl_down(m, off, 64);
      int oi = __shfl_down(mi_, off, 64);
      if (om < m) { m = om; mi_ = oi; }
    }
    mi_ = __shfl(mi_, 0, 64);
    if (ln == 0) sel[w][jj] = mi_;
    ds[w][mi_] = FLT_MAX;
  }
  __syncthreads();
  #pragma unroll
  for (int rr = 0; rr < 4; ++rr) {                     // ctx_sm into x[rr][512..768]
    float m = -FLT_MAX;
    #pragma unroll
    for (int jj = 0; jj < 3; ++jj) m = fmaxf(m, out_m[(size_t)sel[rr][jj] * C + t]);
    x[rr][512 + t] = m - x[rr][t];
  }
  __syncthreads();
  {                                                    // ctx_sg dist: 4 q x 256 refs
    #pragma unroll
    for (int kk = 0; kk < 4; ++kk) {
      int ri = ln + (kk << 6);
      const float4* rp = reinterpret_cast<const float4*>(out_g + (size_t)ri * C);
      float dx = 0.f, dy = 0.f, dz = 0.f, dw = 0.f;
      #pragma unroll 8
      for (int i = 0; i < 64; ++i) {
        float4 a = rp[i];
        float4 q4 = *reinterpret_cast<const float4*>(&x[w][i << 2]);
        float e;
        e = a.x - q4.x; dx = fmaf(e, e, dx);
        e = a.y - q4.y; dy = fmaf(e, e, dy);
        e = a.z - q4.z; dz = fmaf(e, e, dz);
        e = a.w - q4.w; dw = fmaf(e, e, dw);
      }
      ds[w][ri] = (dx + dy) + (dz + dw);
    }
  }
  __syncthreads();
  for (int jj = 0; jj < 4; ++jj) {                     // top-4 per row over 256 refs
    float m = ds[w][ln]; int mi_ = ln;
    #pragma unroll
    for (int o = 64; o < 256; o += 64) {
      float v = ds[w][ln + o];
      if (v < m) { m = v; mi_ = ln + o; }
    }
    #pragma unroll
    for (int off = 32; off; off >>= 1) {
      float om = __shfl_down(m, off, 64);
      int oi = __shfl_down(mi_, off, 64);
      if (om < m) { m = om; mi_ = oi; }
    }
    mi_ = __shfl(mi_, 0, 64);
    if (ln == 0) sel[w][jj] = mi_;
    ds[w][mi_] = FLT_MAX;
  }
  __syncthreads();
  #pragma unroll
  for (int rr = 0; rr < 4; ++rr) {                     // ctx_sg into x[rr][768..1024]
    float m = -FLT_MAX;
    #pragma unroll
    for (int jj = 0; jj < 4; ++jj) m = fmaxf(m, out_g[(size_t)sel[rr][jj] * C + t]);
    x[rr][768 + t] = m - x[rr][t];
  }
  __syncthreads();
  float acc[4] = {0.f, 0.f, 0.f, 0.f};                 // GEMM nin=1024
  for (int i0 = 0; i0 < 1024; i0 += 8) {
    float wv[8];
    #pragma unroll
    for (int u = 0; u < 8; ++u) wv[u] = W[(size_t)(i0 + u) * C + t];
    #pragma unroll
    for (int u = 0; u < 8; ++u) {
      #pragma unroll
      for (int rr = 0; rr < 4; ++rr) acc[rr] = fmaf(x[rr][i0 + u], wv[u], acc[rr]);
    }
  }
  float bv = bias[t];
  float y[4], d[4];
  #pragma unroll
  for (int rr = 0; rr < 4; ++rr) {
    y[rr] = x[rr][t] + acc[rr] + bv;
    float sum = y[rr];
    #pragma unroll
    for (int off = 32; off; off >>= 1) sum += __shfl_down(sum, off, 64);
    if (ln == 0) red[w][rr] = sum;
  }
  __syncthreads();
  float mu[4];
  #pragma unroll
  for (int rr = 0; rr < 4; ++rr)
    mu[rr] = (red[0][rr] + red[1][rr] + red[2][rr] + red[3][rr]) * (1.f / C);
  __syncthreads();
  #pragma unroll
  for (int rr = 0; rr < 4; ++rr) {
    d[rr] = y[rr] - mu[rr];
    float sq = d[rr] * d[rr];
    #pragma unroll
    for (int off = 32; off; off >>= 1) sq += __shfl_down(sq, off, 64);
    if (ln == 0) red[w][rr] = sq;
  }
  __syncthreads();
  #pragma unroll
  for (int rr = 0; rr < 4; ++rr) {
    float var = (red[0][rr] + red[1][rr] + red[2][rr] + red[3][rr]) * (1.f / C);
    out[(size_t)(row0 + rr) * C + t] = d[rr] * rsqrtf(var + 1e-5f) * gamma[t] + beta[t];
  }
}

extern "C" void kernel_launch(void* const* d_in, const int* in_sizes, int n_in,
                              void* d_out, int out_size, void* d_ws, size_t ws_size,
                              hipStream_t stream) {
  const float* patch   = (const float*)d_in[0];
  const float* mood_e  = (const float*)d_in[1];
  const float* genre_e = (const float*)d_in[2];
  const float* sub_e   = (const float*)d_in[3];
  const float* Wm  = (const float*)d_in[4];
  const float* bm  = (const float*)d_in[5];
  const float* Wg  = (const float*)d_in[6];
  const float* bg  = (const float*)d_in[7];
  const float* Ws  = (const float*)d_in[8];
  const float* bs_ = (const float*)d_in[9];
  const float* gm  = (const float*)d_in[10];
  const float* bnm = (const float*)d_in[11];
  const float* gg  = (const float*)d_in[12];
  const float* bng = (const float*)d_in[13];
  const float* gs  = (const float*)d_in[14];
  const float* bns = (const float*)d_in[15];

  char* ws = (char*)d_ws;
  size_t off = 0;
  auto alloc = [&](size_t bytes) { void* p = ws + off; off = (off + bytes + 255) & ~(size_t)255; return p; };
  unsigned short* patchB = (unsigned short*)alloc((size_t)N_PATCH * C * 2);   // 51.2 MB
  unsigned short* lblB   = (unsigned short*)alloc((size_t)S_TOT * C * 2);
  float* hp2   = (float*)alloc((size_t)N_PATCH * 4);
  float* candS = (float*)alloc((size_t)S_TOT * NCAND * 4);
  int*   candI = (int*)  alloc((size_t)S_TOT * NCAND * 4);
  float* ctx_m  = (float*)alloc((size_t)64   * C * 4);
  float* ctx_gp = (float*)alloc((size_t)256  * C * 4);
  float* ctx_sp = (float*)alloc((size_t)1024 * C * 4);

  float* out_m = (float*)d_out;
  float* out_g = out_m + 64 * C;
  float* out_s = out_g + 256 * C;

  k_prep<<<N_PATCH / 4 + S_TOT / 4, 256, 0, stream>>>(patch, mood_e, genre_e, sub_e,
                                                      patchB, lblB, hp2);
  k_score_mfma<<<NGRP * NCHUNK, 256, 0, stream>>>((const char*)patchB, (const char*)lblB,
                                                  hp2, candS, candI);
  k_rescore_ctx<<<S_TOT, 256, 0, stream>>>(patch, mood_e, genre_e, sub_e, hp2,
                                           candS, candI, ctx_m, ctx_gp, ctx_sp);
  k_out<2><<<32, 256, 0, stream>>>(mood_e, ctx_m, nullptr, nullptr, Wm, bm, gm, bnm,
                                   out_m, 512);
  k_out_g<<<128, 256, 0, stream>>>(genre_e, ctx_gp, out_m, Wg, bg, gg, bng, out_g);
  k_out_s<<<256, 256, 0, stream>>>(sub_e, ctx_sp, out_m, out_g, Ws, bs_, gs, bns, out_s);
}